// Round 1
// baseline (1955.970 us; speedup 1.0000x reference)
//
#include <hip/hip_runtime.h>
#include <math.h>

#define B_  2
#define T_  2048
#define C_  1024
#define H_  16
#define S_  16
#define HD_ 64

__device__ __forceinline__ float softplus_f(float v) {
    return fmaxf(v, 0.f) + log1pf(__expf(-fabsf(v)));
}

// ---------------------------------------------------------------------------
// Generic fp32 GEMM: out = A(M,K) @ W(K,N) + bias
// outMode: 0 = row-major MxN
//          1 = heads layout ((b*H+h)*T + t)*HD + hd   (m = b*T+t, n = h*HD+hd)
//          2 = transposed (b*C + n)*T + t             (m = b*T+t)
// act:     0 = none, 1 = softplus
// Tiles: 64x64, BK=16, 256 threads, 4x4 micro-tile.
// ---------------------------------------------------------------------------
__global__ __launch_bounds__(256) void gemm64(
    const float* __restrict__ A, const float* __restrict__ W,
    const float* __restrict__ bias, float* __restrict__ out,
    int M, int N, int K, int outMode, int act)
{
    __shared__ float As[16][68];
    __shared__ float Ws[16][68];

    const int tid = threadIdx.x;
    const int ty = tid >> 4;        // 0..15
    const int tx = tid & 15;        // 0..15
    const int mBase = blockIdx.y * 64;
    const int nBase = blockIdx.x * 64;

    float acc[4][4] = {};

    const int lr = tid >> 2;              // 0..63 row in A-tile
    const int lk = (tid & 3) << 2;        // k offset (x4)
    const int wr = tid >> 4;              // 0..15 k-row in W-tile
    const int wc = (tid & 15) << 2;       // col offset (x4)

    for (int k0 = 0; k0 < K; k0 += 16) {
        float4 av = *(const float4*)&A[(size_t)(mBase + lr) * K + k0 + lk];
        float4 wv = *(const float4*)&W[(size_t)(k0 + wr) * N + nBase + wc];
        __syncthreads();
        As[lk + 0][lr] = av.x;
        As[lk + 1][lr] = av.y;
        As[lk + 2][lr] = av.z;
        As[lk + 3][lr] = av.w;
        *(float4*)&Ws[wr][wc] = wv;
        __syncthreads();
#pragma unroll
        for (int kk = 0; kk < 16; ++kk) {
            float4 a = *(const float4*)&As[kk][ty * 4];
            float4 b = *(const float4*)&Ws[kk][tx * 4];
            float ar[4] = {a.x, a.y, a.z, a.w};
            float br[4] = {b.x, b.y, b.z, b.w};
#pragma unroll
            for (int i = 0; i < 4; ++i)
#pragma unroll
                for (int j = 0; j < 4; ++j)
                    acc[i][j] = fmaf(ar[i], br[j], acc[i][j]);
        }
    }

    if (outMode == 0 || outMode == 1) {
        const float4 bv = *(const float4*)&bias[nBase + tx * 4];
        const float br[4] = {bv.x, bv.y, bv.z, bv.w};
#pragma unroll
        for (int i = 0; i < 4; ++i) {
            int m = mBase + ty * 4 + i;
            float v[4];
#pragma unroll
            for (int j = 0; j < 4; ++j) {
                v[j] = acc[i][j] + br[j];
                if (act == 1) v[j] = softplus_f(v[j]);
            }
            float4 o4 = {v[0], v[1], v[2], v[3]};
            if (outMode == 0) {
                *(float4*)&out[(size_t)m * N + nBase + tx * 4] = o4;
            } else {
                int b = m >> 11, t = m & (T_ - 1);
                int n0 = nBase + tx * 4;
                int h = n0 >> 6, hd = n0 & 63;
                *(float4*)&out[(((size_t)(b * H_ + h)) * T_ + t) * HD_ + hd] = o4;
            }
        }
    } else { // transposed (b*C + n)*T + t, store along m (t)
        int m0 = mBase + ty * 4;
        int b = m0 >> 11, t0 = m0 & (T_ - 1);
#pragma unroll
        for (int j = 0; j < 4; ++j) {
            int n = nBase + tx * 4 + j;
            float bb = bias[n];
            float v[4];
#pragma unroll
            for (int i = 0; i < 4; ++i) {
                v[i] = acc[i][j] + bb;
                if (act == 1) v[i] = softplus_f(v[i]);
            }
            float4 o4 = {v[0], v[1], v[2], v[3]};
            *(float4*)&out[((size_t)b * C_ + n) * T_ + t0] = o4;
        }
    }
}

// ---------------------------------------------------------------------------
// Small projections: Bm = x @ WB, Cm = x @ WC  (N = S = 16), written transposed
// to (b, s, t). One thread per (m, s) pair computing both outputs.
// ---------------------------------------------------------------------------
__global__ __launch_bounds__(256) void bc_proj(
    const float* __restrict__ x, const float* __restrict__ WB,
    const float* __restrict__ WC, float* __restrict__ BmT,
    float* __restrict__ CmT)
{
    int gid = blockIdx.x * 256 + threadIdx.x;   // 0 .. B*T*S-1
    int s = gid & 15;
    int m = gid >> 4;                            // 0..B*T-1
    int b = m >> 11, t = m & (T_ - 1);
    const float* xr = x + (size_t)m * C_;
    float a1 = 0.f, a2 = 0.f;
#pragma unroll 8
    for (int k = 0; k < C_; ++k) {
        float xv = xr[k];
        a1 = fmaf(xv, WB[k * S_ + s], a1);
        a2 = fmaf(xv, WC[k * S_ + s], a2);
    }
    BmT[((size_t)b * S_ + s) * T_ + t] = a1;
    CmT[((size_t)b * S_ + s) * T_ + t] = a2;
}

// ---------------------------------------------------------------------------
// Sequential scan over T. One thread per (b, c, s). Blocks: 16 c x 16 s.
// Inputs deltaT/xbaseT in (b,c,t), BmT/CmT in (b,s,t).
// Output hyb = x_base + y in (b,t,c).
// ---------------------------------------------------------------------------
__global__ __launch_bounds__(256) void scan_kernel(
    const float* __restrict__ xbaseT, const float* __restrict__ deltaT,
    const float* __restrict__ BmT, const float* __restrict__ CmT,
    const float* __restrict__ A_log, float* __restrict__ hyb)
{
    const int tid = threadIdx.x;
    const int s = tid & 15;
    const int cl = tid >> 4;                 // 0..15
    const int b = blockIdx.x >> 6;           // C/16 = 64 groups per batch
    const int cg = blockIdx.x & 63;
    const int c = cg * 16 + cl;

    const float a = -__expf(A_log[c * S_ + s]);

    const float* dp = deltaT + ((size_t)b * C_ + c) * T_;
    const float* xp = xbaseT + ((size_t)b * C_ + c) * T_;
    const float* bp = BmT + ((size_t)b * S_ + s) * T_;
    const float* cp = CmT + ((size_t)b * S_ + s) * T_;
    float* hp = hyb + (size_t)b * T_ * C_ + c;

    float h = 0.f;
    for (int t0 = 0; t0 < T_; t0 += 4) {
        float4 d4 = *(const float4*)&dp[t0];
        float4 x4 = *(const float4*)&xp[t0];
        float4 b4 = *(const float4*)&bp[t0];
        float4 c4 = *(const float4*)&cp[t0];
        float dv[4] = {d4.x, d4.y, d4.z, d4.w};
        float xv[4] = {x4.x, x4.y, x4.z, x4.w};
        float bv[4] = {b4.x, b4.y, b4.z, b4.w};
        float cv[4] = {c4.x, c4.y, c4.z, c4.w};
#pragma unroll
        for (int q = 0; q < 4; ++q) {
            float bar = __expf(dv[q] * a);
            h = fmaf(bar, h, dv[q] * xv[q] * bv[q]);
            float contrib = h * cv[q];
            contrib += __shfl_xor(contrib, 1, 64);
            contrib += __shfl_xor(contrib, 2, 64);
            contrib += __shfl_xor(contrib, 4, 64);
            contrib += __shfl_xor(contrib, 8, 64);
            if (s == 0) hp[(size_t)(t0 + q) * C_] = xv[q] + contrib;
        }
    }
}

// ---------------------------------------------------------------------------
// LayerNorm over C=1024. One block (256 threads) per row.
// ---------------------------------------------------------------------------
__global__ __launch_bounds__(256) void layernorm_kernel(
    const float* __restrict__ in, const float* __restrict__ g,
    const float* __restrict__ beta, float* __restrict__ out)
{
    const int row = blockIdx.x;
    const float* rp = in + (size_t)row * C_;
    const int c = threadIdx.x * 4;
    float4 v = *(const float4*)&rp[c];
    float sum = v.x + v.y + v.z + v.w;
    float sq = v.x * v.x + v.y * v.y + v.z * v.z + v.w * v.w;
#pragma unroll
    for (int off = 1; off < 64; off <<= 1) {
        sum += __shfl_xor(sum, off, 64);
        sq += __shfl_xor(sq, off, 64);
    }
    __shared__ float sS[4], sQ[4];
    int wave = threadIdx.x >> 6, lane = threadIdx.x & 63;
    if (lane == 0) { sS[wave] = sum; sQ[wave] = sq; }
    __syncthreads();
    sum = sS[0] + sS[1] + sS[2] + sS[3];
    sq = sQ[0] + sQ[1] + sQ[2] + sQ[3];
    const float mu = sum * (1.f / C_);
    const float var = sq * (1.f / C_) - mu * mu;
    const float rstd = rsqrtf(var + 1e-5f);
    float4 gg = *(const float4*)&g[c];
    float4 bb = *(const float4*)&beta[c];
    float4 o4;
    o4.x = (v.x - mu) * rstd * gg.x + bb.x;
    o4.y = (v.y - mu) * rstd * gg.y + bb.y;
    o4.z = (v.z - mu) * rstd * gg.z + bb.z;
    o4.w = (v.w - mu) * rstd * gg.w + bb.w;
    *(float4*)&out[(size_t)row * C_ + c] = o4;
}

// ---------------------------------------------------------------------------
// Causal flash attention, fp32. Q,K,V in heads layout (b,h,t,hd).
// BQ=32 query rows per block, key tiles of 64. 128 threads, 4x4 micro-tiles.
// Output attn_out in (b,t,h,hd) == row-major (B*T, C).
// ---------------------------------------------------------------------------
#define BQ 32
#define BK 64
__global__ __launch_bounds__(128) void attn_kernel(
    const float* __restrict__ Q, const float* __restrict__ K,
    const float* __restrict__ V, const float* __restrict__ temp,
    float* __restrict__ out)
{
    __shared__ float Qs[BQ][68];
    __shared__ float Ks[BK][68];
    __shared__ float Vs[BK][68];
    __shared__ float Ps[BQ][68];

    const int tid = threadIdx.x;            // 128
    const int tx = tid & 15;                // 0..15 (key / out cols)
    const int ty = tid >> 4;                // 0..7  (query rows)
    const int qi = blockIdx.x & 63;         // T/BQ = 64
    const int bh = blockIdx.x >> 6;         // 0..B*H-1
    const int qbase = qi * BQ;
    const int b = bh >> 4, h = bh & 15;

    const float scale = softplus_f(temp[h]) * 0.125f;   // 1/sqrt(64)

    const float* Qp = Q + (size_t)bh * T_ * HD_;
    const float* Kp = K + (size_t)bh * T_ * HD_;
    const float* Vp = V + (size_t)bh * T_ * HD_;

    // load Q tile (32 x 64)
    {
        int cq = (tid & 15) * 4;
#pragma unroll
        for (int i = 0; i < 4; ++i) {
            int r = (tid >> 4) + i * 8;
            *(float4*)&Qs[r][cq] =
                *(const float4*)&Qp[(size_t)(qbase + r) * HD_ + cq];
        }
    }

    float m_i[4], l_i[4], o[4][4];
#pragma unroll
    for (int i = 0; i < 4; ++i) {
        m_i[i] = -INFINITY;
        l_i[i] = 0.f;
#pragma unroll
        for (int j = 0; j < 4; ++j) o[i][j] = 0.f;
    }

    const int nT = (qbase + BQ + BK - 1) / BK;
    for (int jt = 0; jt < nT; ++jt) {
        const int kbase = jt * BK;
        __syncthreads();
        {
            int cq = (tid & 15) * 4;
#pragma unroll
            for (int i = 0; i < 8; ++i) {
                int r = (tid >> 4) + i * 8;
                *(float4*)&Ks[r][cq] =
                    *(const float4*)&Kp[(size_t)(kbase + r) * HD_ + cq];
                *(float4*)&Vs[r][cq] =
                    *(const float4*)&Vp[(size_t)(kbase + r) * HD_ + cq];
            }
        }
        __syncthreads();

        // S = Q K^T
        float sacc[4][4] = {};
#pragma unroll
        for (int d4 = 0; d4 < 16; ++d4) {
            float4 qv[4], kv[4];
#pragma unroll
            for (int i = 0; i < 4; ++i) qv[i] = *(const float4*)&Qs[ty * 4 + i][d4 * 4];
#pragma unroll
            for (int j = 0; j < 4; ++j) kv[j] = *(const float4*)&Ks[tx * 4 + j][d4 * 4];
#pragma unroll
            for (int i = 0; i < 4; ++i)
#pragma unroll
                for (int j = 0; j < 4; ++j) {
                    sacc[i][j] = fmaf(qv[i].x, kv[j].x, sacc[i][j]);
                    sacc[i][j] = fmaf(qv[i].y, kv[j].y, sacc[i][j]);
                    sacc[i][j] = fmaf(qv[i].z, kv[j].z, sacc[i][j]);
                    sacc[i][j] = fmaf(qv[i].w, kv[j].w, sacc[i][j]);
                }
        }

        // scale + causal mask
#pragma unroll
        for (int i = 0; i < 4; ++i) {
            int qrow = qbase + ty * 4 + i;
#pragma unroll
            for (int j = 0; j < 4; ++j) {
                int kcol = kbase + tx * 4 + j;
                float sv = sacc[i][j] * scale;
                sacc[i][j] = (kcol > qrow) ? -INFINITY : sv;
            }
        }

        // online softmax update
#pragma unroll
        for (int i = 0; i < 4; ++i) {
            float mx = fmaxf(fmaxf(sacc[i][0], sacc[i][1]),
                             fmaxf(sacc[i][2], sacc[i][3]));
            mx = fmaxf(mx, __shfl_xor(mx, 1, 64));
            mx = fmaxf(mx, __shfl_xor(mx, 2, 64));
            mx = fmaxf(mx, __shfl_xor(mx, 4, 64));
            mx = fmaxf(mx, __shfl_xor(mx, 8, 64));
            float m_new = fmaxf(m_i[i], mx);
            float alpha = __expf(m_i[i] - m_new);
            m_i[i] = m_new;
            l_i[i] *= alpha;
#pragma unroll
            for (int j = 0; j < 4; ++j) o[i][j] *= alpha;
            float p[4], rs = 0.f;
#pragma unroll
            for (int j = 0; j < 4; ++j) {
                p[j] = __expf(sacc[i][j] - m_new);
                rs += p[j];
            }
            float4 p4 = {p[0], p[1], p[2], p[3]};
            *(float4*)&Ps[ty * 4 + i][tx * 4] = p4;
            rs += __shfl_xor(rs, 1, 64);
            rs += __shfl_xor(rs, 2, 64);
            rs += __shfl_xor(rs, 4, 64);
            rs += __shfl_xor(rs, 8, 64);
            l_i[i] += rs;
        }
        __syncthreads();

        // O += P @ V
#pragma unroll
        for (int k4 = 0; k4 < 16; ++k4) {
            float4 pv[4], vv[4];
#pragma unroll
            for (int i = 0; i < 4; ++i) pv[i] = *(const float4*)&Ps[ty * 4 + i][k4 * 4];
#pragma unroll
            for (int q = 0; q < 4; ++q) vv[q] = *(const float4*)&Vs[k4 * 4 + q][tx * 4];
#pragma unroll
            for (int i = 0; i < 4; ++i) {
                float pr[4] = {pv[i].x, pv[i].y, pv[i].z, pv[i].w};
#pragma unroll
                for (int q = 0; q < 4; ++q) {
                    o[i][0] = fmaf(pr[q], vv[q].x, o[i][0]);
                    o[i][1] = fmaf(pr[q], vv[q].y, o[i][1]);
                    o[i][2] = fmaf(pr[q], vv[q].z, o[i][2]);
                    o[i][3] = fmaf(pr[q], vv[q].w, o[i][3]);
                }
            }
        }
    }

    // epilogue: divide by l, write (b, t, h, hd)
#pragma unroll
    for (int i = 0; i < 4; ++i) {
        float inv = 1.f / l_i[i];
        int q = qbase + ty * 4 + i;
        float4 o4 = {o[i][0] * inv, o[i][1] * inv, o[i][2] * inv, o[i][3] * inv};
        *(float4*)&out[(((size_t)b * T_ + q) * H_ + h) * HD_ + tx * 4] = o4;
    }
}

// ---------------------------------------------------------------------------
extern "C" void kernel_launch(void* const* d_in, const int* in_sizes, int n_in,
                              void* d_out, int out_size, void* d_ws, size_t ws_size,
                              hipStream_t stream)
{
    const float* x     = (const float*)d_in[0];
    const float* A_log = (const float*)d_in[1];
    const float* Wd    = (const float*)d_in[2];
    const float* bd    = (const float*)d_in[3];
    const float* WB    = (const float*)d_in[4];
    const float* WC    = (const float*)d_in[5];
    const float* Wq    = (const float*)d_in[6];
    const float* bq    = (const float*)d_in[7];
    const float* Wk    = (const float*)d_in[8];
    const float* bk    = (const float*)d_in[9];
    const float* Wv    = (const float*)d_in[10];
    const float* bv    = (const float*)d_in[11];
    const float* Wx    = (const float*)d_in[12];
    const float* bx    = (const float*)d_in[13];
    const float* Wo    = (const float*)d_in[14];
    const float* bo    = (const float*)d_in[15];
    const float* ln_g  = (const float*)d_in[16];
    const float* ln_b  = (const float*)d_in[17];
    const float* temp  = (const float*)d_in[18];

    float* ws = (float*)d_ws;
    const size_t NBIG = (size_t)B_ * T_ * C_;   // 4194304
    float* deltaT = ws;                  // slot0: deltaT -> Q
    float* xbaseT = ws + NBIG;           // slot1: xbaseT -> K
    float* hyb    = ws + 2 * NBIG;       // slot2: hyb   -> V
    float* hybrid = ws + 3 * NBIG;       // slot3: hybrid -> attn_out
    float* BmT    = ws + 4 * NBIG;
    float* CmT    = BmT + (size_t)B_ * S_ * T_;

    const int M = B_ * T_;
    dim3 gGemm(C_ / 64, M / 64);

    // projections (transposed outputs for the scan)
    gemm64<<<gGemm, 256, 0, stream>>>(x, Wx, bx, xbaseT, M, C_, C_, 2, 0);
    gemm64<<<gGemm, 256, 0, stream>>>(x, Wd, bd, deltaT, M, C_, C_, 2, 1);
    bc_proj<<<(B_ * T_ * S_) / 256, 256, 0, stream>>>(x, WB, WC, BmT, CmT);

    // sequential scan -> hyb = x_base + y  (b,t,c)
    scan_kernel<<<B_ * C_ / 16, 256, 0, stream>>>(xbaseT, deltaT, BmT, CmT,
                                                  A_log, hyb);

    // layernorm -> hybrid
    layernorm_kernel<<<B_ * T_, 256, 0, stream>>>(hyb, ln_g, ln_b, hybrid);

    // QKV projections (heads layout)
    float* Qb = deltaT;
    float* Kb = xbaseT;
    float* Vb = hyb;
    gemm64<<<gGemm, 256, 0, stream>>>(hybrid, Wq, bq, Qb, M, C_, C_, 1, 0);
    gemm64<<<gGemm, 256, 0, stream>>>(hybrid, Wk, bk, Kb, M, C_, C_, 1, 0);
    gemm64<<<gGemm, 256, 0, stream>>>(hybrid, Wv, bv, Vb, M, C_, C_, 1, 0);

    // causal flash attention
    float* attnOut = hybrid;
    attn_kernel<<<B_ * H_ * (T_ / BQ), 128, 0, stream>>>(Qb, Kb, Vb, temp,
                                                         attnOut);

    // final projection
    gemm64<<<gGemm, 256, 0, stream>>>(attnOut, Wo, bo, (float*)d_out,
                                      M, C_, C_, 0, 0);
}

// Round 2
// 936.166 us; speedup vs baseline: 2.0893x; 2.0893x over previous
//
#include <hip/hip_runtime.h>
#include <math.h>

#define B_  2
#define T_  2048
#define C_  1024
#define H_  16
#define S_  16
#define HD_ 64

typedef short  short8  __attribute__((ext_vector_type(8)));
typedef unsigned short ushort8 __attribute__((ext_vector_type(8)));
typedef unsigned short ushort4v __attribute__((ext_vector_type(4)));
typedef float  f32x4   __attribute__((ext_vector_type(4)));

__device__ __forceinline__ float softplus_f(float v) {
    return fmaxf(v, 0.f) + log1pf(__expf(-fabsf(v)));
}

__device__ __forceinline__ unsigned short f2bf(float x) {
    unsigned u = __float_as_uint(x);
    u += 0x7fffu + ((u >> 16) & 1u);
    return (unsigned short)(u >> 16);
}

// ---------------------------------------------------------------------------
// cast fp32 -> bf16 (vectorized), n4 = n/4
// ---------------------------------------------------------------------------
__global__ __launch_bounds__(256) void cast_bf16(const float* __restrict__ in,
                                                 unsigned short* __restrict__ out,
                                                 int n4)
{
    int i = blockIdx.x * 256 + threadIdx.x;
    if (i >= n4) return;
    float4 v = ((const float4*)in)[i];
    ushort4v o = {f2bf(v.x), f2bf(v.y), f2bf(v.z), f2bf(v.w)};
    ((ushort4v*)out)[i] = o;
}

// ---------------------------------------------------------------------------
// transpose-cast: W (K x N fp32, row-major) -> WT (N x K bf16, row-major)
// K = N = 1024. grid (N/32, K/32), block 256.
// ---------------------------------------------------------------------------
__global__ __launch_bounds__(256) void wtrans(const float* __restrict__ W,
                                              unsigned short* __restrict__ WT)
{
    __shared__ float t[32][33];
    const int n0 = blockIdx.x * 32, k0 = blockIdx.y * 32;
    const int tx = threadIdx.x & 31, ty = threadIdx.x >> 5;   // ty 0..7
#pragma unroll
    for (int p = 0; p < 4; ++p)
        t[ty + p * 8][tx] = W[(size_t)(k0 + ty + p * 8) * C_ + n0 + tx];
    __syncthreads();
#pragma unroll
    for (int p = 0; p < 4; ++p)
        WT[(size_t)(n0 + ty + p * 8) * C_ + k0 + tx] = f2bf(t[tx][ty + p * 8]);
}

// ---------------------------------------------------------------------------
// bf16 MFMA GEMM: out = A(M x K) @ B(N x K)^T + bias   (both K-major bf16)
// 128x128 tile, BK=32, 256 threads = 4 waves (2x2 of 64x64).
// LDS in fragment order (16B chunks), filled via global_load_lds width=16,
// double-buffered.
// modes: 0: fp32 out[m*N+n]                       bias[n]
//        1: bf16 heads out[((b*H+h)*T+t)*HD+hd]   (m=b*T+t, n=h*64+hd) bias[n]
//        2: fp32 out[(b*C+m)*T+t]                 (n=b*T+t) bias[m], opt softplus
//        3: bf16 out[((b*H+h)*HD+hd)*T+t]         (m=h*64+hd, n=b*T+t) bias[m]
// ---------------------------------------------------------------------------
__global__ __launch_bounds__(256) void gemm_mfma(
    const unsigned short* __restrict__ A, const unsigned short* __restrict__ Bm,
    const float* __restrict__ bias, void* __restrict__ outv,
    int M, int N, int K, int mode, int act)
{
    __shared__ __align__(16) unsigned short As[2][4096];  // 512 chunks x 8 bf16
    __shared__ __align__(16) unsigned short Bs[2][4096];

    const int tid = threadIdx.x;
    const int w = tid >> 6, lane = tid & 63;
    const int lq = lane & 15, lg = lane >> 4;
    const int wm = w >> 1, wn = w & 1;
    const int mBase = blockIdx.y * 128, nBase = blockIdx.x * 128;

    // chunk c: ti = c>>6 (16-row tile), g = (c>>4)&3 (k-group), mrow = c&15
    const int c0 = tid, c1 = tid + 256;
    const int rA0 = ((c0 >> 6) << 4) + (c0 & 15), kO0 = ((c0 >> 4) & 3) << 3;
    const int rA1 = ((c1 >> 6) << 4) + (c1 & 15), kO1 = ((c1 >> 4) & 3) << 3;

    f32x4 acc[4][4];
#pragma unroll
    for (int i = 0; i < 4; ++i)
#pragma unroll
        for (int j = 0; j < 4; ++j) acc[i][j] = (f32x4){0.f, 0.f, 0.f, 0.f};

    const unsigned short* ga0 = A  + (size_t)(mBase + rA0) * K + kO0;
    const unsigned short* ga1 = A  + (size_t)(mBase + rA1) * K + kO1;
    const unsigned short* gb0 = Bm + (size_t)(nBase + rA0) * K + kO0;
    const unsigned short* gb1 = Bm + (size_t)(nBase + rA1) * K + kO1;

    #define LOAD_TILES(k0v, bufv)                                              \
        do {                                                                   \
            __builtin_amdgcn_global_load_lds(                                  \
                (const __attribute__((address_space(1))) void*)(ga0 + (k0v)),  \
                (__attribute__((address_space(3))) void*)&As[bufv][(w * 64) * 8],        16, 0, 0); \
            __builtin_amdgcn_global_load_lds(                                  \
                (const __attribute__((address_space(1))) void*)(ga1 + (k0v)),  \
                (__attribute__((address_space(3))) void*)&As[bufv][(256 + w * 64) * 8],  16, 0, 0); \
            __builtin_amdgcn_global_load_lds(                                  \
                (const __attribute__((address_space(1))) void*)(gb0 + (k0v)),  \
                (__attribute__((address_space(3))) void*)&Bs[bufv][(w * 64) * 8],        16, 0, 0); \
            __builtin_amdgcn_global_load_lds(                                  \
                (const __attribute__((address_space(1))) void*)(gb1 + (k0v)),  \
                (__attribute__((address_space(3))) void*)&Bs[bufv][(256 + w * 64) * 8],  16, 0, 0); \
        } while (0)

    int buf = 0;
    LOAD_TILES(0, 0);
    for (int k0 = 0; k0 < K; k0 += 32) {
        __syncthreads();
        if (k0 + 32 < K) LOAD_TILES(k0 + 32, buf ^ 1);
        short8 a[4], b[4];
#pragma unroll
        for (int i = 0; i < 4; ++i)
            a[i] = *(const short8*)&As[buf][((wm * 4 + i) * 64 + lg * 16 + lq) * 8];
#pragma unroll
        for (int j = 0; j < 4; ++j)
            b[j] = *(const short8*)&Bs[buf][((wn * 4 + j) * 64 + lg * 16 + lq) * 8];
#pragma unroll
        for (int i = 0; i < 4; ++i)
#pragma unroll
            for (int j = 0; j < 4; ++j)
                acc[i][j] = __builtin_amdgcn_mfma_f32_16x16x32_bf16(
                    a[i], b[j], acc[i][j], 0, 0, 0);
        buf ^= 1;
    }
    #undef LOAD_TILES

    // epilogue
    if (mode == 0) {
        float* O = (float*)outv;
#pragma unroll
        for (int i = 0; i < 4; ++i) {
            int Rb = mBase + wm * 64 + i * 16 + lg * 4;
#pragma unroll
            for (int j = 0; j < 4; ++j) {
                int Cg = nBase + wn * 64 + j * 16 + lq;
                float bb = bias[Cg];
#pragma unroll
                for (int r = 0; r < 4; ++r)
                    O[(size_t)(Rb + r) * N + Cg] = acc[i][j][r] + bb;
            }
        }
    } else if (mode == 1) {
        unsigned short* O = (unsigned short*)outv;
#pragma unroll
        for (int i = 0; i < 4; ++i) {
            int Rb = mBase + wm * 64 + i * 16 + lg * 4;
#pragma unroll
            for (int j = 0; j < 4; ++j) {
                int Cg = nBase + wn * 64 + j * 16 + lq;
                float bb = bias[Cg];
                int h = Cg >> 6, hd = Cg & 63;
#pragma unroll
                for (int r = 0; r < 4; ++r) {
                    int R = Rb + r, bidx = R >> 11, t = R & (T_ - 1);
                    O[(((size_t)(bidx * H_ + h) * T_ + t) * HD_) + hd] =
                        f2bf(acc[i][j][r] + bb);
                }
            }
        }
    } else if (mode == 2) {
        float* O = (float*)outv;
#pragma unroll
        for (int i = 0; i < 4; ++i) {
            int Rb = mBase + wm * 64 + i * 16 + lg * 4;
#pragma unroll
            for (int j = 0; j < 4; ++j) {
                int Cg = nBase + wn * 64 + j * 16 + lq;
                int bidx = Cg >> 11, t = Cg & (T_ - 1);
#pragma unroll
                for (int r = 0; r < 4; ++r) {
                    int R = Rb + r;
                    float v = acc[i][j][r] + bias[R];
                    if (act) v = softplus_f(v);
                    O[((size_t)bidx * C_ + R) * T_ + t] = v;
                }
            }
        }
    } else { // mode 3
        unsigned short* O = (unsigned short*)outv;
#pragma unroll
        for (int i = 0; i < 4; ++i) {
            int Rb = mBase + wm * 64 + i * 16 + lg * 4;
#pragma unroll
            for (int j = 0; j < 4; ++j) {
                int Cg = nBase + wn * 64 + j * 16 + lq;
                int bidx = Cg >> 11, t = Cg & (T_ - 1);
#pragma unroll
                for (int r = 0; r < 4; ++r) {
                    int R = Rb + r;
                    int h = R >> 6, hd = R & 63;
                    O[(((size_t)(bidx * H_ + h) * HD_ + hd) * T_) + t] =
                        f2bf(acc[i][j][r] + bias[R]);
                }
            }
        }
    }
}

// ---------------------------------------------------------------------------
// Small projections: Bm = x @ WB, Cm = x @ WC  (N = S = 16), transposed (b,s,t)
// ---------------------------------------------------------------------------
__global__ __launch_bounds__(256) void bc_proj(
    const float* __restrict__ x, const float* __restrict__ WB,
    const float* __restrict__ WC, float* __restrict__ BmT,
    float* __restrict__ CmT)
{
    int gid = blockIdx.x * 256 + threadIdx.x;
    int s = gid & 15;
    int m = gid >> 4;
    int b = m >> 11, t = m & (T_ - 1);
    const float* xr = x + (size_t)m * C_;
    float a1 = 0.f, a2 = 0.f;
#pragma unroll 8
    for (int k = 0; k < C_; ++k) {
        float xv = xr[k];
        a1 = fmaf(xv, WB[k * S_ + s], a1);
        a2 = fmaf(xv, WC[k * S_ + s], a2);
    }
    BmT[((size_t)b * S_ + s) * T_ + t] = a1;
    CmT[((size_t)b * S_ + s) * T_ + t] = a2;
}

// ---------------------------------------------------------------------------
// Sequential scan over T. One thread per (b, c, s).
// ---------------------------------------------------------------------------
__global__ __launch_bounds__(256) void scan_kernel(
    const float* __restrict__ xbaseT, const float* __restrict__ deltaT,
    const float* __restrict__ BmT, const float* __restrict__ CmT,
    const float* __restrict__ A_log, float* __restrict__ hyb)
{
    const int tid = threadIdx.x;
    const int s = tid & 15;
    const int cl = tid >> 4;
    const int b = blockIdx.x >> 6;
    const int cg = blockIdx.x & 63;
    const int c = cg * 16 + cl;

    const float a = -__expf(A_log[c * S_ + s]);

    const float* dp = deltaT + ((size_t)b * C_ + c) * T_;
    const float* xp = xbaseT + ((size_t)b * C_ + c) * T_;
    const float* bp = BmT + ((size_t)b * S_ + s) * T_;
    const float* cp = CmT + ((size_t)b * S_ + s) * T_;
    float* hp = hyb + (size_t)b * T_ * C_ + c;

    float h = 0.f;
    for (int t0 = 0; t0 < T_; t0 += 4) {
        float4 d4 = *(const float4*)&dp[t0];
        float4 x4 = *(const float4*)&xp[t0];
        float4 b4 = *(const float4*)&bp[t0];
        float4 c4 = *(const float4*)&cp[t0];
        float dv[4] = {d4.x, d4.y, d4.z, d4.w};
        float xv[4] = {x4.x, x4.y, x4.z, x4.w};
        float bv[4] = {b4.x, b4.y, b4.z, b4.w};
        float cv[4] = {c4.x, c4.y, c4.z, c4.w};
#pragma unroll
        for (int q = 0; q < 4; ++q) {
            float bar = __expf(dv[q] * a);
            h = fmaf(bar, h, dv[q] * xv[q] * bv[q]);
            float contrib = h * cv[q];
            contrib += __shfl_xor(contrib, 1, 64);
            contrib += __shfl_xor(contrib, 2, 64);
            contrib += __shfl_xor(contrib, 4, 64);
            contrib += __shfl_xor(contrib, 8, 64);
            if (s == 0) hp[(size_t)(t0 + q) * C_] = xv[q] + contrib;
        }
    }
}

// ---------------------------------------------------------------------------
// LayerNorm over C=1024, bf16 output.
// ---------------------------------------------------------------------------
__global__ __launch_bounds__(256) void layernorm_kernel(
    const float* __restrict__ in, const float* __restrict__ g,
    const float* __restrict__ beta, unsigned short* __restrict__ out)
{
    const int row = blockIdx.x;
    const float* rp = in + (size_t)row * C_;
    const int c = threadIdx.x * 4;
    float4 v = *(const float4*)&rp[c];
    float sum = v.x + v.y + v.z + v.w;
    float sq = v.x * v.x + v.y * v.y + v.z * v.z + v.w * v.w;
#pragma unroll
    for (int off = 1; off < 64; off <<= 1) {
        sum += __shfl_xor(sum, off, 64);
        sq += __shfl_xor(sq, off, 64);
    }
    __shared__ float sS[4], sQ[4];
    int wave = threadIdx.x >> 6, lane = threadIdx.x & 63;
    if (lane == 0) { sS[wave] = sum; sQ[wave] = sq; }
    __syncthreads();
    sum = sS[0] + sS[1] + sS[2] + sS[3];
    sq = sQ[0] + sQ[1] + sQ[2] + sQ[3];
    const float mu = sum * (1.f / C_);
    const float var = sq * (1.f / C_) - mu * mu;
    const float rstd = rsqrtf(var + 1e-5f);
    float4 gg = *(const float4*)&g[c];
    float4 bb = *(const float4*)&beta[c];
    ushort4v o;
    o.x = f2bf((v.x - mu) * rstd * gg.x + bb.x);
    o.y = f2bf((v.y - mu) * rstd * gg.y + bb.y);
    o.z = f2bf((v.z - mu) * rstd * gg.z + bb.z);
    o.w = f2bf((v.w - mu) * rstd * gg.w + bb.w);
    *(ushort4v*)&out[(size_t)row * C_ + c] = o;
}

// ---------------------------------------------------------------------------
// MFMA flash attention (bf16 inputs, fp32 accum).
// Q,K: (b,h,t,64) bf16. VT: (b,h,64,t) bf16. out: (b,t,h*64+hd) bf16.
// Block: 256 thr / 4 waves; Q-tile 64 (16 rows/wave); K-tile 64.
// ---------------------------------------------------------------------------
#define AP 72   // padded row length (bf16): 36 words -> stride 4 mod 32 banks
__global__ __launch_bounds__(256) void attn_mfma(
    const unsigned short* __restrict__ Q, const unsigned short* __restrict__ K,
    const unsigned short* __restrict__ VT, const float* __restrict__ temp,
    unsigned short* __restrict__ out)
{
    __shared__ __align__(16) unsigned short Qs[64 * AP];
    __shared__ __align__(16) unsigned short Ks[64 * AP];
    __shared__ __align__(16) unsigned short Vs[64 * AP];
    __shared__ __align__(16) unsigned short Ps[4 * 16 * AP];

    const int tid = threadIdx.x;
    const int w = tid >> 6, lane = tid & 63;
    const int lq = lane & 15, lg = lane >> 4;
    const int qi = blockIdx.x & 31;
    const int bh = blockIdx.x >> 5;
    const int b = bh >> 4, h = bh & 15;
    const int qbase = qi * 64;

    const float scale = softplus_f(temp[h]) * 0.125f;

    const unsigned short* Qp = Q + (size_t)bh * T_ * HD_ + (size_t)qbase * HD_;
    const unsigned short* Kp = K + (size_t)bh * T_ * HD_;
    const unsigned short* Vp = VT + (size_t)bh * HD_ * T_;

    // Q tile: 64 rows x 64 bf16; chunk c: row=c>>3, off=(c&7)*8
    {
        int c0 = tid, c1 = tid + 256;
        int r0 = c0 >> 3, o0 = (c0 & 7) << 3;
        int r1 = c1 >> 3, o1 = (c1 & 7) << 3;
        *(ushort8*)&Qs[r0 * AP + o0] = *(const ushort8*)&Qp[(size_t)r0 * HD_ + o0];
        *(ushort8*)&Qs[r1 * AP + o1] = *(const ushort8*)&Qp[(size_t)r1 * HD_ + o1];
    }

    float m_i[4], l_i[4];
    f32x4 o[4];
#pragma unroll
    for (int r = 0; r < 4; ++r) { m_i[r] = -INFINITY; l_i[r] = 0.f; }
#pragma unroll
    for (int j = 0; j < 4; ++j) o[j] = (f32x4){0.f, 0.f, 0.f, 0.f};

    const int nT = qbase / 64 + 1;
    for (int jt = 0; jt < nT; ++jt) {
        const int kbase = jt * 64;
        const bool last = (jt == nT - 1);
        __syncthreads();
        {
            int c0 = tid, c1 = tid + 256;
            int r0 = c0 >> 3, o0 = (c0 & 7) << 3;
            int r1 = c1 >> 3, o1 = (c1 & 7) << 3;
            *(ushort8*)&Ks[r0 * AP + o0] =
                *(const ushort8*)&Kp[(size_t)(kbase + r0) * HD_ + o0];
            *(ushort8*)&Ks[r1 * AP + o1] =
                *(const ushort8*)&Kp[(size_t)(kbase + r1) * HD_ + o1];
            *(ushort8*)&Vs[r0 * AP + o0] =
                *(const ushort8*)&Vp[(size_t)r0 * T_ + kbase + o0];
            *(ushort8*)&Vs[r1 * AP + o1] =
                *(const ushort8*)&Vp[(size_t)r1 * T_ + kbase + o1];
        }
        __syncthreads();

        // S = Q K^T  (per wave: 16 q-rows x 64 keys)
        f32x4 sacc[4];
#pragma unroll
        for (int j = 0; j < 4; ++j) sacc[j] = (f32x4){0.f, 0.f, 0.f, 0.f};
#pragma unroll
        for (int s = 0; s < 2; ++s) {
            short8 qf = *(const short8*)&Qs[(w * 16 + lq) * AP + s * 32 + lg * 8];
#pragma unroll
            for (int j = 0; j < 4; ++j) {
                short8 kf = *(const short8*)&Ks[(j * 16 + lq) * AP + s * 32 + lg * 8];
                sacc[j] = __builtin_amdgcn_mfma_f32_16x16x32_bf16(qf, kf, sacc[j], 0, 0, 0);
            }
        }

        // online softmax (rows: qbase + w*16 + lg*4 + r; cols: kbase + j*16 + lq)
#pragma unroll
        for (int r = 0; r < 4; ++r) {
            int qrow = qbase + w * 16 + lg * 4 + r;
            float sv[4];
#pragma unroll
            for (int j = 0; j < 4; ++j) {
                sv[j] = sacc[j][r] * scale;
                if (last && (kbase + j * 16 + lq > qrow)) sv[j] = -INFINITY;
            }
            float mx = fmaxf(fmaxf(sv[0], sv[1]), fmaxf(sv[2], sv[3]));
            mx = fmaxf(mx, __shfl_xor(mx, 1, 64));
            mx = fmaxf(mx, __shfl_xor(mx, 2, 64));
            mx = fmaxf(mx, __shfl_xor(mx, 4, 64));
            mx = fmaxf(mx, __shfl_xor(mx, 8, 64));
            float mnew = fmaxf(m_i[r], mx);
            float alpha = __expf(m_i[r] - mnew);
            float p[4], rs = 0.f;
#pragma unroll
            for (int j = 0; j < 4; ++j) { p[j] = __expf(sv[j] - mnew); rs += p[j]; }
            rs += __shfl_xor(rs, 1, 64);
            rs += __shfl_xor(rs, 2, 64);
            rs += __shfl_xor(rs, 4, 64);
            rs += __shfl_xor(rs, 8, 64);
            l_i[r] = l_i[r] * alpha + rs;
            m_i[r] = mnew;
#pragma unroll
            for (int j = 0; j < 4; ++j) o[j][r] *= alpha;
#pragma unroll
            for (int j = 0; j < 4; ++j)
                Ps[(w * 16 + lg * 4 + r) * AP + j * 16 + lq] = f2bf(p[j]);
        }

        // O += P @ V   (P wave-private in LDS; V^T rows are dims)
#pragma unroll
        for (int s = 0; s < 2; ++s) {
            short8 pf = *(const short8*)&Ps[(w * 16 + lq) * AP + s * 32 + lg * 8];
#pragma unroll
            for (int j = 0; j < 4; ++j) {
                short8 vf = *(const short8*)&Vs[(j * 16 + lq) * AP + s * 32 + lg * 8];
                o[j] = __builtin_amdgcn_mfma_f32_16x16x32_bf16(pf, vf, o[j], 0, 0, 0);
            }
        }
    }

    // epilogue
#pragma unroll
    for (int r = 0; r < 4; ++r) {
        float inv = 1.f / l_i[r];
        int qrow = qbase + w * 16 + lg * 4 + r;
#pragma unroll
        for (int j = 0; j < 4; ++j)
            out[((size_t)(b * T_ + qrow)) * C_ + h * 64 + j * 16 + lq] =
                f2bf(o[j][r] * inv);
    }
}

// ---------------------------------------------------------------------------
extern "C" void kernel_launch(void* const* d_in, const int* in_sizes, int n_in,
                              void* d_out, int out_size, void* d_ws, size_t ws_size,
                              hipStream_t stream)
{
    const float* x     = (const float*)d_in[0];
    const float* A_log = (const float*)d_in[1];
    const float* Wd    = (const float*)d_in[2];
    const float* bd    = (const float*)d_in[3];
    const float* WB    = (const float*)d_in[4];
    const float* WC    = (const float*)d_in[5];
    const float* Wq    = (const float*)d_in[6];
    const float* bq    = (const float*)d_in[7];
    const float* Wk    = (const float*)d_in[8];
    const float* bk    = (const float*)d_in[9];
    const float* Wv    = (const float*)d_in[10];
    const float* bv    = (const float*)d_in[11];
    const float* Wx    = (const float*)d_in[12];
    const float* bx    = (const float*)d_in[13];
    const float* Wo    = (const float*)d_in[14];
    const float* bo    = (const float*)d_in[15];
    const float* ln_g  = (const float*)d_in[16];
    const float* ln_b  = (const float*)d_in[17];
    const float* temp  = (const float*)d_in[18];

    char* wsb = (char*)d_ws;
    const size_t MB = 1024 * 1024;
    unsigned short* xb     = (unsigned short*)(wsb);            // 8 MB (later hybrid)
    unsigned short* WxT    = (unsigned short*)(wsb + 8 * MB);   // 2 MB each
    unsigned short* WdT    = (unsigned short*)(wsb + 10 * MB);
    unsigned short* WqT    = (unsigned short*)(wsb + 12 * MB);
    unsigned short* WkT    = (unsigned short*)(wsb + 14 * MB);
    unsigned short* WvT    = (unsigned short*)(wsb + 16 * MB);
    unsigned short* WoT    = (unsigned short*)(wsb + 18 * MB);
    float* deltaT          = (float*)(wsb + 20 * MB);           // 16 MB
    float* xbaseT          = (float*)(wsb + 36 * MB);           // 16 MB
    float* hyb             = (float*)(wsb + 52 * MB);           // 16 MB
    float* BmT             = (float*)(wsb + 68 * MB);           // 256 KB
    float* CmT             = (float*)(wsb + 68 * MB + 256 * 1024);
    unsigned short* hybrid = (unsigned short*)(wsb);            // reuse xb
    unsigned short* Qb     = (unsigned short*)(wsb + 20 * MB);  // reuse deltaT
    unsigned short* Kb     = (unsigned short*)(wsb + 28 * MB);
    unsigned short* VTb    = (unsigned short*)(wsb + 36 * MB);  // reuse xbaseT
    unsigned short* attnO  = (unsigned short*)(wsb + 44 * MB);

    // prep: casts + weight transposes
    cast_bf16<<<4096, 256, 0, stream>>>(x, xb, (B_ * T_ * C_) / 4);
    dim3 gT(32, 32);
    wtrans<<<gT, 256, 0, stream>>>(Wx, WxT);
    wtrans<<<gT, 256, 0, stream>>>(Wd, WdT);
    wtrans<<<gT, 256, 0, stream>>>(Wq, WqT);
    wtrans<<<gT, 256, 0, stream>>>(Wk, WkT);
    wtrans<<<gT, 256, 0, stream>>>(Wv, WvT);
    wtrans<<<gT, 256, 0, stream>>>(Wo, WoT);

    // x_base / delta (transposed (b,c,t) via swapped operands)
    dim3 gSw(32, 8);   // N=4096 cols, M=1024 rows
    gemm_mfma<<<gSw, 256, 0, stream>>>(WxT, xb, bx, xbaseT, 1024, 4096, 1024, 2, 0);
    gemm_mfma<<<gSw, 256, 0, stream>>>(WdT, xb, bd, deltaT, 1024, 4096, 1024, 2, 1);

    bc_proj<<<(B_ * T_ * S_) / 256, 256, 0, stream>>>(x, WB, WC, BmT, CmT);

    scan_kernel<<<B_ * C_ / 16, 256, 0, stream>>>(xbaseT, deltaT, BmT, CmT,
                                                  A_log, hyb);

    layernorm_kernel<<<B_ * T_, 256, 0, stream>>>(hyb, ln_g, ln_b, hybrid);

    // QKV
    dim3 gNm(8, 32);   // N=1024 cols, M=4096 rows
    gemm_mfma<<<gNm, 256, 0, stream>>>(hybrid, WqT, bq, Qb, 4096, 1024, 1024, 1, 0);
    gemm_mfma<<<gNm, 256, 0, stream>>>(hybrid, WkT, bk, Kb, 4096, 1024, 1024, 1, 0);
    gemm_mfma<<<gSw, 256, 0, stream>>>(WvT, hybrid, bv, VTb, 1024, 4096, 1024, 3, 0);

    attn_mfma<<<B_ * H_ * (T_ / 64), 256, 0, stream>>>(Qb, Kb, VTb, temp, attnO);

    gemm_mfma<<<gNm, 256, 0, stream>>>(attnO, WoT, bo, d_out, 4096, 1024, 1024, 0, 0);
}

// Round 3
// 667.802 us; speedup vs baseline: 2.9290x; 1.4019x over previous
//
#include <hip/hip_runtime.h>
#include <math.h>

#define B_  2
#define T_  2048
#define C_  1024
#define H_  16
#define S_  16
#define HD_ 64
#define NCH 32
#define CHL 64   /* T_/NCH */

typedef short  short8  __attribute__((ext_vector_type(8)));
typedef unsigned short ushort8 __attribute__((ext_vector_type(8)));
typedef unsigned short ushort4v __attribute__((ext_vector_type(4)));
typedef float  f32x4   __attribute__((ext_vector_type(4)));

__device__ __forceinline__ float softplus_f(float v) {
    return fmaxf(v, 0.f) + log1pf(__expf(-fabsf(v)));
}

__device__ __forceinline__ unsigned short f2bf(float x) {
    unsigned u = __float_as_uint(x);
    u += 0x7fffu + ((u >> 16) & 1u);
    return (unsigned short)(u >> 16);
}

// ---------------------------------------------------------------------------
// cast fp32 -> bf16 (vectorized), n4 = n/4
// ---------------------------------------------------------------------------
__global__ __launch_bounds__(256) void cast_bf16(const float* __restrict__ in,
                                                 unsigned short* __restrict__ out,
                                                 int n4)
{
    int i = blockIdx.x * 256 + threadIdx.x;
    if (i >= n4) return;
    float4 v = ((const float4*)in)[i];
    ushort4v o = {f2bf(v.x), f2bf(v.y), f2bf(v.z), f2bf(v.w)};
    ((ushort4v*)out)[i] = o;
}

// ---------------------------------------------------------------------------
// transpose-cast: W (K x N fp32, row-major) -> WT (N x K bf16, row-major)
// ---------------------------------------------------------------------------
__global__ __launch_bounds__(256) void wtrans(const float* __restrict__ W,
                                              unsigned short* __restrict__ WT)
{
    __shared__ float t[32][33];
    const int n0 = blockIdx.x * 32, k0 = blockIdx.y * 32;
    const int tx = threadIdx.x & 31, ty = threadIdx.x >> 5;
#pragma unroll
    for (int p = 0; p < 4; ++p)
        t[ty + p * 8][tx] = W[(size_t)(k0 + ty + p * 8) * C_ + n0 + tx];
    __syncthreads();
#pragma unroll
    for (int p = 0; p < 4; ++p)
        WT[(size_t)(n0 + ty + p * 8) * C_ + k0 + tx] = f2bf(t[tx][ty + p * 8]);
}

// ---------------------------------------------------------------------------
// bf16 MFMA GEMM: out = A(M x K) @ B(N x K)^T + bias   (both K-major bf16)
// 128x128 tile, BK=32, 256 threads = 4 waves (2x2 of 64x64).
// modes: 0: fp32 out[m*N+n]                       bias[n]
//        1: bf16 heads out[((b*H+h)*T+t)*HD+hd]   (m=b*T+t, n=h*64+hd) bias[n]
//        2: fp32 out[(b*C+m)*T+t]                 (n=b*T+t) bias[m], opt softplus
//        3: bf16 out[((b*H+h)*HD+hd)*T+t]         (m=h*64+hd, n=b*T+t) bias[m]
// ---------------------------------------------------------------------------
__global__ __launch_bounds__(256) void gemm_mfma(
    const unsigned short* __restrict__ A, const unsigned short* __restrict__ Bm,
    const float* __restrict__ bias, void* __restrict__ outv,
    int M, int N, int K, int mode, int act)
{
    __shared__ __align__(16) unsigned short As[2][4096];
    __shared__ __align__(16) unsigned short Bs[2][4096];

    const int tid = threadIdx.x;
    const int w = tid >> 6, lane = tid & 63;
    const int lq = lane & 15, lg = lane >> 4;
    const int wm = w >> 1, wn = w & 1;
    const int mBase = blockIdx.y * 128, nBase = blockIdx.x * 128;

    const int c0 = tid, c1 = tid + 256;
    const int rA0 = ((c0 >> 6) << 4) + (c0 & 15), kO0 = ((c0 >> 4) & 3) << 3;
    const int rA1 = ((c1 >> 6) << 4) + (c1 & 15), kO1 = ((c1 >> 4) & 3) << 3;

    f32x4 acc[4][4];
#pragma unroll
    for (int i = 0; i < 4; ++i)
#pragma unroll
        for (int j = 0; j < 4; ++j) acc[i][j] = (f32x4){0.f, 0.f, 0.f, 0.f};

    const unsigned short* ga0 = A  + (size_t)(mBase + rA0) * K + kO0;
    const unsigned short* ga1 = A  + (size_t)(mBase + rA1) * K + kO1;
    const unsigned short* gb0 = Bm + (size_t)(nBase + rA0) * K + kO0;
    const unsigned short* gb1 = Bm + (size_t)(nBase + rA1) * K + kO1;

    #define LOAD_TILES(k0v, bufv)                                              \
        do {                                                                   \
            __builtin_amdgcn_global_load_lds(                                  \
                (const __attribute__((address_space(1))) void*)(ga0 + (k0v)),  \
                (__attribute__((address_space(3))) void*)&As[bufv][(w * 64) * 8],        16, 0, 0); \
            __builtin_amdgcn_global_load_lds(                                  \
                (const __attribute__((address_space(1))) void*)(ga1 + (k0v)),  \
                (__attribute__((address_space(3))) void*)&As[bufv][(256 + w * 64) * 8],  16, 0, 0); \
            __builtin_amdgcn_global_load_lds(                                  \
                (const __attribute__((address_space(1))) void*)(gb0 + (k0v)),  \
                (__attribute__((address_space(3))) void*)&Bs[bufv][(w * 64) * 8],        16, 0, 0); \
            __builtin_amdgcn_global_load_lds(                                  \
                (const __attribute__((address_space(1))) void*)(gb1 + (k0v)),  \
                (__attribute__((address_space(3))) void*)&Bs[bufv][(256 + w * 64) * 8],  16, 0, 0); \
        } while (0)

    int buf = 0;
    LOAD_TILES(0, 0);
    for (int k0 = 0; k0 < K; k0 += 32) {
        __syncthreads();
        if (k0 + 32 < K) LOAD_TILES(k0 + 32, buf ^ 1);
        short8 a[4], b[4];
#pragma unroll
        for (int i = 0; i < 4; ++i)
            a[i] = *(const short8*)&As[buf][((wm * 4 + i) * 64 + lg * 16 + lq) * 8];
#pragma unroll
        for (int j = 0; j < 4; ++j)
            b[j] = *(const short8*)&Bs[buf][((wn * 4 + j) * 64 + lg * 16 + lq) * 8];
#pragma unroll
        for (int i = 0; i < 4; ++i)
#pragma unroll
            for (int j = 0; j < 4; ++j)
                acc[i][j] = __builtin_amdgcn_mfma_f32_16x16x32_bf16(
                    a[i], b[j], acc[i][j], 0, 0, 0);
        buf ^= 1;
    }
    #undef LOAD_TILES

    if (mode == 0) {
        float* O = (float*)outv;
#pragma unroll
        for (int i = 0; i < 4; ++i) {
            int Rb = mBase + wm * 64 + i * 16 + lg * 4;
#pragma unroll
            for (int j = 0; j < 4; ++j) {
                int Cg = nBase + wn * 64 + j * 16 + lq;
                float bb = bias[Cg];
#pragma unroll
                for (int r = 0; r < 4; ++r)
                    O[(size_t)(Rb + r) * N + Cg] = acc[i][j][r] + bb;
            }
        }
    } else if (mode == 1) {
        unsigned short* O = (unsigned short*)outv;
#pragma unroll
        for (int i = 0; i < 4; ++i) {
            int Rb = mBase + wm * 64 + i * 16 + lg * 4;
#pragma unroll
            for (int j = 0; j < 4; ++j) {
                int Cg = nBase + wn * 64 + j * 16 + lq;
                float bb = bias[Cg];
                int h = Cg >> 6, hd = Cg & 63;
#pragma unroll
                for (int r = 0; r < 4; ++r) {
                    int R = Rb + r, bidx = R >> 11, t = R & (T_ - 1);
                    O[(((size_t)(bidx * H_ + h) * T_ + t) * HD_) + hd] =
                        f2bf(acc[i][j][r] + bb);
                }
            }
        }
    } else if (mode == 2) {
        float* O = (float*)outv;
#pragma unroll
        for (int i = 0; i < 4; ++i) {
            int Rb = mBase + wm * 64 + i * 16 + lg * 4;
#pragma unroll
            for (int j = 0; j < 4; ++j) {
                int Cg = nBase + wn * 64 + j * 16 + lq;
                int bidx = Cg >> 11, t = Cg & (T_ - 1);
#pragma unroll
                for (int r = 0; r < 4; ++r) {
                    int R = Rb + r;
                    float v = acc[i][j][r] + bias[R];
                    if (act) v = softplus_f(v);
                    O[((size_t)bidx * C_ + R) * T_ + t] = v;
                }
            }
        }
    } else {
        unsigned short* O = (unsigned short*)outv;
#pragma unroll
        for (int i = 0; i < 4; ++i) {
            int Rb = mBase + wm * 64 + i * 16 + lg * 4;
#pragma unroll
            for (int j = 0; j < 4; ++j) {
                int Cg = nBase + wn * 64 + j * 16 + lq;
                int bidx = Cg >> 11, t = Cg & (T_ - 1);
#pragma unroll
                for (int r = 0; r < 4; ++r) {
                    int R = Rb + r;
                    int h = R >> 6, hd = R & 63;
                    O[(((size_t)(bidx * H_ + h) * HD_ + hd) * T_) + t] =
                        f2bf(acc[i][j][r] + bias[R]);
                }
            }
        }
    }
}

// ---------------------------------------------------------------------------
// Small projections: Bm = x @ WB, Cm = x @ WC, transposed (b,s,t)
// ---------------------------------------------------------------------------
__global__ __launch_bounds__(256) void bc_proj(
    const float* __restrict__ x, const float* __restrict__ WB,
    const float* __restrict__ WC, float* __restrict__ BmT,
    float* __restrict__ CmT)
{
    int gid = blockIdx.x * 256 + threadIdx.x;
    int s = gid & 15;
    int m = gid >> 4;
    int b = m >> 11, t = m & (T_ - 1);
    const float* xr = x + (size_t)m * C_;
    float a1 = 0.f, a2 = 0.f;
#pragma unroll 8
    for (int k = 0; k < C_; ++k) {
        float xv = xr[k];
        a1 = fmaf(xv, WB[k * S_ + s], a1);
        a2 = fmaf(xv, WC[k * S_ + s], a2);
    }
    BmT[((size_t)b * S_ + s) * T_ + t] = a1;
    CmT[((size_t)b * S_ + s) * T_ + t] = a2;
}

// ---------------------------------------------------------------------------
// Chunked scan, pass 1: per (b,c,s,chunk) compute
//   L = local scan of u_t = d*x*B with h0=0, over CHL steps
//   P = prod bar_t = exp(a * sum d_t)
// grid: blockIdx.x = ((b*NCH + k)*64 + cg), 256 thr = 16c x 16s
// ---------------------------------------------------------------------------
__global__ __launch_bounds__(256) void scan_partial(
    const float* __restrict__ xbaseT, const float* __restrict__ deltaT,
    const float* __restrict__ BmT, const float* __restrict__ A_log,
    float* __restrict__ Pbuf, float* __restrict__ Lbuf)
{
    const int tid = threadIdx.x;
    const int s = tid & 15;
    const int cl = tid >> 4;
    const int cg = blockIdx.x & 63;
    const int k  = (blockIdx.x >> 6) & (NCH - 1);
    const int b  = blockIdx.x >> 11;
    const int c  = cg * 16 + cl;

    const float a = -__expf(A_log[c * S_ + s]);
    const int tb = k * CHL;
    const float* dp = deltaT + ((size_t)b * C_ + c) * T_ + tb;
    const float* xp = xbaseT + ((size_t)b * C_ + c) * T_ + tb;
    const float* bp = BmT + ((size_t)b * S_ + s) * T_ + tb;

    float L = 0.f, sumd = 0.f;
    for (int t0 = 0; t0 < CHL; t0 += 4) {
        float4 d4 = *(const float4*)&dp[t0];
        float4 x4 = *(const float4*)&xp[t0];
        float4 b4 = *(const float4*)&bp[t0];
        float dv[4] = {d4.x, d4.y, d4.z, d4.w};
        float xv[4] = {x4.x, x4.y, x4.z, x4.w};
        float bv[4] = {b4.x, b4.y, b4.z, b4.w};
#pragma unroll
        for (int q = 0; q < 4; ++q) {
            float bar = __expf(dv[q] * a);
            L = fmaf(bar, L, dv[q] * xv[q] * bv[q]);
            sumd += dv[q];
        }
    }
    int idx = (blockIdx.x << 8) + tid;
    Pbuf[idx] = __expf(a * sumd);
    Lbuf[idx] = L;
}

// ---------------------------------------------------------------------------
// Chunked scan, pass 2: combine predecessor (P,L) in-thread, then re-scan the
// chunk producing y and hyb = x_base + y in (b,t,c).
// ---------------------------------------------------------------------------
__global__ __launch_bounds__(256) void scan_final(
    const float* __restrict__ xbaseT, const float* __restrict__ deltaT,
    const float* __restrict__ BmT, const float* __restrict__ CmT,
    const float* __restrict__ A_log, const float* __restrict__ Pbuf,
    const float* __restrict__ Lbuf, float* __restrict__ hyb)
{
    const int tid = threadIdx.x;
    const int s = tid & 15;
    const int cl = tid >> 4;
    const int cg = blockIdx.x & 63;
    const int k  = (blockIdx.x >> 6) & (NCH - 1);
    const int b  = blockIdx.x >> 11;
    const int c  = cg * 16 + cl;

    // combine chunk summaries k' < k  (k is block-uniform)
    float h = 0.f;
    for (int k2 = 0; k2 < k; ++k2) {
        int idx = ((((b << 5) | k2) << 6 | cg) << 8) | tid;
        h = fmaf(Pbuf[idx], h, Lbuf[idx]);
    }

    const float a = -__expf(A_log[c * S_ + s]);
    const int tb = k * CHL;
    const float* dp = deltaT + ((size_t)b * C_ + c) * T_ + tb;
    const float* xp = xbaseT + ((size_t)b * C_ + c) * T_ + tb;
    const float* bp = BmT + ((size_t)b * S_ + s) * T_ + tb;
    const float* cp = CmT + ((size_t)b * S_ + s) * T_ + tb;
    float* hp = hyb + ((size_t)b * T_ + tb) * C_ + c;

    for (int t0 = 0; t0 < CHL; t0 += 4) {
        float4 d4 = *(const float4*)&dp[t0];
        float4 x4 = *(const float4*)&xp[t0];
        float4 b4 = *(const float4*)&bp[t0];
        float4 c4 = *(const float4*)&cp[t0];
        float dv[4] = {d4.x, d4.y, d4.z, d4.w};
        float xv[4] = {x4.x, x4.y, x4.z, x4.w};
        float bv[4] = {b4.x, b4.y, b4.z, b4.w};
        float cv[4] = {c4.x, c4.y, c4.z, c4.w};
#pragma unroll
        for (int q = 0; q < 4; ++q) {
            float bar = __expf(dv[q] * a);
            h = fmaf(bar, h, dv[q] * xv[q] * bv[q]);
            float contrib = h * cv[q];
            contrib += __shfl_xor(contrib, 1, 64);
            contrib += __shfl_xor(contrib, 2, 64);
            contrib += __shfl_xor(contrib, 4, 64);
            contrib += __shfl_xor(contrib, 8, 64);
            if (s == 0) hp[(size_t)(t0 + q) * C_] = xv[q] + contrib;
        }
    }
}

// ---------------------------------------------------------------------------
// LayerNorm over C=1024, bf16 output.
// ---------------------------------------------------------------------------
__global__ __launch_bounds__(256) void layernorm_kernel(
    const float* __restrict__ in, const float* __restrict__ g,
    const float* __restrict__ beta, unsigned short* __restrict__ out)
{
    const int row = blockIdx.x;
    const float* rp = in + (size_t)row * C_;
    const int c = threadIdx.x * 4;
    float4 v = *(const float4*)&rp[c];
    float sum = v.x + v.y + v.z + v.w;
    float sq = v.x * v.x + v.y * v.y + v.z * v.z + v.w * v.w;
#pragma unroll
    for (int off = 1; off < 64; off <<= 1) {
        sum += __shfl_xor(sum, off, 64);
        sq += __shfl_xor(sq, off, 64);
    }
    __shared__ float sS[4], sQ[4];
    int wave = threadIdx.x >> 6, lane = threadIdx.x & 63;
    if (lane == 0) { sS[wave] = sum; sQ[wave] = sq; }
    __syncthreads();
    sum = sS[0] + sS[1] + sS[2] + sS[3];
    sq = sQ[0] + sQ[1] + sQ[2] + sQ[3];
    const float mu = sum * (1.f / C_);
    const float var = sq * (1.f / C_) - mu * mu;
    const float rstd = rsqrtf(var + 1e-5f);
    float4 gg = *(const float4*)&g[c];
    float4 bb = *(const float4*)&beta[c];
    ushort4v o;
    o.x = f2bf((v.x - mu) * rstd * gg.x + bb.x);
    o.y = f2bf((v.y - mu) * rstd * gg.y + bb.y);
    o.z = f2bf((v.z - mu) * rstd * gg.z + bb.z);
    o.w = f2bf((v.w - mu) * rstd * gg.w + bb.w);
    *(ushort4v*)&out[(size_t)row * C_ + c] = o;
}

// ---------------------------------------------------------------------------
// MFMA flash attention (bf16 inputs, fp32 accum).
// ---------------------------------------------------------------------------
#define AP 72
__global__ __launch_bounds__(256) void attn_mfma(
    const unsigned short* __restrict__ Q, const unsigned short* __restrict__ K,
    const unsigned short* __restrict__ VT, const float* __restrict__ temp,
    unsigned short* __restrict__ out)
{
    __shared__ __align__(16) unsigned short Qs[64 * AP];
    __shared__ __align__(16) unsigned short Ks[64 * AP];
    __shared__ __align__(16) unsigned short Vs[64 * AP];
    __shared__ __align__(16) unsigned short Ps[4 * 16 * AP];

    const int tid = threadIdx.x;
    const int w = tid >> 6, lane = tid & 63;
    const int lq = lane & 15, lg = lane >> 4;
    const int qi = blockIdx.x & 31;
    const int bh = blockIdx.x >> 5;
    const int b = bh >> 4, h = bh & 15;
    const int qbase = qi * 64;

    const float scale = softplus_f(temp[h]) * 0.125f;

    const unsigned short* Qp = Q + (size_t)bh * T_ * HD_ + (size_t)qbase * HD_;
    const unsigned short* Kp = K + (size_t)bh * T_ * HD_;
    const unsigned short* Vp = VT + (size_t)bh * HD_ * T_;

    {
        int c0 = tid, c1 = tid + 256;
        int r0 = c0 >> 3, o0 = (c0 & 7) << 3;
        int r1 = c1 >> 3, o1 = (c1 & 7) << 3;
        *(ushort8*)&Qs[r0 * AP + o0] = *(const ushort8*)&Qp[(size_t)r0 * HD_ + o0];
        *(ushort8*)&Qs[r1 * AP + o1] = *(const ushort8*)&Qp[(size_t)r1 * HD_ + o1];
    }

    float m_i[4], l_i[4];
    f32x4 o[4];
#pragma unroll
    for (int r = 0; r < 4; ++r) { m_i[r] = -INFINITY; l_i[r] = 0.f; }
#pragma unroll
    for (int j = 0; j < 4; ++j) o[j] = (f32x4){0.f, 0.f, 0.f, 0.f};

    const int nT = qbase / 64 + 1;
    for (int jt = 0; jt < nT; ++jt) {
        const int kbase = jt * 64;
        const bool last = (jt == nT - 1);
        __syncthreads();
        {
            int c0 = tid, c1 = tid + 256;
            int r0 = c0 >> 3, o0 = (c0 & 7) << 3;
            int r1 = c1 >> 3, o1 = (c1 & 7) << 3;
            *(ushort8*)&Ks[r0 * AP + o0] =
                *(const ushort8*)&Kp[(size_t)(kbase + r0) * HD_ + o0];
            *(ushort8*)&Ks[r1 * AP + o1] =
                *(const ushort8*)&Kp[(size_t)(kbase + r1) * HD_ + o1];
            *(ushort8*)&Vs[r0 * AP + o0] =
                *(const ushort8*)&Vp[(size_t)r0 * T_ + kbase + o0];
            *(ushort8*)&Vs[r1 * AP + o1] =
                *(const ushort8*)&Vp[(size_t)r1 * T_ + kbase + o1];
        }
        __syncthreads();

        f32x4 sacc[4];
#pragma unroll
        for (int j = 0; j < 4; ++j) sacc[j] = (f32x4){0.f, 0.f, 0.f, 0.f};
#pragma unroll
        for (int s = 0; s < 2; ++s) {
            short8 qf = *(const short8*)&Qs[(w * 16 + lq) * AP + s * 32 + lg * 8];
#pragma unroll
            for (int j = 0; j < 4; ++j) {
                short8 kf = *(const short8*)&Ks[(j * 16 + lq) * AP + s * 32 + lg * 8];
                sacc[j] = __builtin_amdgcn_mfma_f32_16x16x32_bf16(qf, kf, sacc[j], 0, 0, 0);
            }
        }

#pragma unroll
        for (int r = 0; r < 4; ++r) {
            int qrow = qbase + w * 16 + lg * 4 + r;
            float sv[4];
#pragma unroll
            for (int j = 0; j < 4; ++j) {
                sv[j] = sacc[j][r] * scale;
                if (last && (kbase + j * 16 + lq > qrow)) sv[j] = -INFINITY;
            }
            float mx = fmaxf(fmaxf(sv[0], sv[1]), fmaxf(sv[2], sv[3]));
            mx = fmaxf(mx, __shfl_xor(mx, 1, 64));
            mx = fmaxf(mx, __shfl_xor(mx, 2, 64));
            mx = fmaxf(mx, __shfl_xor(mx, 4, 64));
            mx = fmaxf(mx, __shfl_xor(mx, 8, 64));
            float mnew = fmaxf(m_i[r], mx);
            float alpha = __expf(m_i[r] - mnew);
            float p[4], rs = 0.f;
#pragma unroll
            for (int j = 0; j < 4; ++j) { p[j] = __expf(sv[j] - mnew); rs += p[j]; }
            rs += __shfl_xor(rs, 1, 64);
            rs += __shfl_xor(rs, 2, 64);
            rs += __shfl_xor(rs, 4, 64);
            rs += __shfl_xor(rs, 8, 64);
            l_i[r] = l_i[r] * alpha + rs;
            m_i[r] = mnew;
#pragma unroll
            for (int j = 0; j < 4; ++j) o[j][r] *= alpha;
#pragma unroll
            for (int j = 0; j < 4; ++j)
                Ps[(w * 16 + lg * 4 + r) * AP + j * 16 + lq] = f2bf(p[j]);
        }

#pragma unroll
        for (int s = 0; s < 2; ++s) {
            short8 pf = *(const short8*)&Ps[(w * 16 + lq) * AP + s * 32 + lg * 8];
#pragma unroll
            for (int j = 0; j < 4; ++j) {
                short8 vf = *(const short8*)&Vs[(j * 16 + lq) * AP + s * 32 + lg * 8];
                o[j] = __builtin_amdgcn_mfma_f32_16x16x32_bf16(pf, vf, o[j], 0, 0, 0);
            }
        }
    }

#pragma unroll
    for (int r = 0; r < 4; ++r) {
        float inv = 1.f / l_i[r];
        int qrow = qbase + w * 16 + lg * 4 + r;
#pragma unroll
        for (int j = 0; j < 4; ++j)
            out[((size_t)(b * T_ + qrow)) * C_ + h * 64 + j * 16 + lq] =
                f2bf(o[j][r] * inv);
    }
}

// ---------------------------------------------------------------------------
extern "C" void kernel_launch(void* const* d_in, const int* in_sizes, int n_in,
                              void* d_out, int out_size, void* d_ws, size_t ws_size,
                              hipStream_t stream)
{
    const float* x     = (const float*)d_in[0];
    const float* A_log = (const float*)d_in[1];
    const float* Wd    = (const float*)d_in[2];
    const float* bd    = (const float*)d_in[3];
    const float* WB    = (const float*)d_in[4];
    const float* WC    = (const float*)d_in[5];
    const float* Wq    = (const float*)d_in[6];
    const float* bq    = (const float*)d_in[7];
    const float* Wk    = (const float*)d_in[8];
    const float* bk    = (const float*)d_in[9];
    const float* Wv    = (const float*)d_in[10];
    const float* bv    = (const float*)d_in[11];
    const float* Wx    = (const float*)d_in[12];
    const float* bx    = (const float*)d_in[13];
    const float* Wo    = (const float*)d_in[14];
    const float* bo    = (const float*)d_in[15];
    const float* ln_g  = (const float*)d_in[16];
    const float* ln_b  = (const float*)d_in[17];
    const float* temp  = (const float*)d_in[18];

    char* wsb = (char*)d_ws;
    const size_t MB = 1024 * 1024;
    unsigned short* xb     = (unsigned short*)(wsb);            // 8 MB, then P/L, then hybrid
    unsigned short* WxT    = (unsigned short*)(wsb + 8 * MB);
    unsigned short* WdT    = (unsigned short*)(wsb + 10 * MB);
    unsigned short* WqT    = (unsigned short*)(wsb + 12 * MB);
    unsigned short* WkT    = (unsigned short*)(wsb + 14 * MB);
    unsigned short* WvT    = (unsigned short*)(wsb + 16 * MB);
    unsigned short* WoT    = (unsigned short*)(wsb + 18 * MB);
    float* deltaT          = (float*)(wsb + 20 * MB);
    float* xbaseT          = (float*)(wsb + 36 * MB);
    float* hyb             = (float*)(wsb + 52 * MB);
    float* BmT             = (float*)(wsb + 68 * MB);
    float* CmT             = (float*)(wsb + 68 * MB + 256 * 1024);
    float* Pbuf            = (float*)(wsb);                     // 4 MB (xb dead)
    float* Lbuf            = (float*)(wsb + 4 * MB);            // 4 MB
    unsigned short* hybrid = (unsigned short*)(wsb);            // after P/L dead
    unsigned short* Qb     = (unsigned short*)(wsb + 20 * MB);
    unsigned short* Kb     = (unsigned short*)(wsb + 28 * MB);
    unsigned short* VTb    = (unsigned short*)(wsb + 36 * MB);
    unsigned short* attnO  = (unsigned short*)(wsb + 44 * MB);

    cast_bf16<<<4096, 256, 0, stream>>>(x, xb, (B_ * T_ * C_) / 4);
    dim3 gT(32, 32);
    wtrans<<<gT, 256, 0, stream>>>(Wx, WxT);
    wtrans<<<gT, 256, 0, stream>>>(Wd, WdT);
    wtrans<<<gT, 256, 0, stream>>>(Wq, WqT);
    wtrans<<<gT, 256, 0, stream>>>(Wk, WkT);
    wtrans<<<gT, 256, 0, stream>>>(Wv, WvT);
    wtrans<<<gT, 256, 0, stream>>>(Wo, WoT);

    dim3 gSw(32, 8);
    gemm_mfma<<<gSw, 256, 0, stream>>>(WxT, xb, bx, xbaseT, 1024, 4096, 1024, 2, 0);
    gemm_mfma<<<gSw, 256, 0, stream>>>(WdT, xb, bd, deltaT, 1024, 4096, 1024, 2, 1);

    bc_proj<<<(B_ * T_ * S_) / 256, 256, 0, stream>>>(x, WB, WC, BmT, CmT);

    // chunk-parallel scan (P/L overwrite xb, which is dead now)
    const int scanBlocks = B_ * NCH * (C_ / 16);   // 4096
    scan_partial<<<scanBlocks, 256, 0, stream>>>(xbaseT, deltaT, BmT, A_log,
                                                 Pbuf, Lbuf);
    scan_final<<<scanBlocks, 256, 0, stream>>>(xbaseT, deltaT, BmT, CmT, A_log,
                                               Pbuf, Lbuf, hyb);

    layernorm_kernel<<<B_ * T_, 256, 0, stream>>>(hyb, ln_g, ln_b, hybrid);

    dim3 gNm(8, 32);
    gemm_mfma<<<gNm, 256, 0, stream>>>(hybrid, WqT, bq, Qb, 4096, 1024, 1024, 1, 0);
    gemm_mfma<<<gNm, 256, 0, stream>>>(hybrid, WkT, bk, Kb, 4096, 1024, 1024, 1, 0);
    gemm_mfma<<<gSw, 256, 0, stream>>>(WvT, hybrid, bv, VTb, 1024, 4096, 1024, 3, 0);

    attn_mfma<<<B_ * H_ * (T_ / 64), 256, 0, stream>>>(Qb, Kb, VTb, temp, attnO);

    gemm_mfma<<<gNm, 256, 0, stream>>>(attnO, WoT, bo, d_out, 4096, 1024, 1024, 0, 0);
}

// Round 5
// 549.318 us; speedup vs baseline: 3.5607x; 1.2157x over previous
//
#include <hip/hip_runtime.h>
#include <math.h>

#define B_  2
#define T_  2048
#define C_  1024
#define H_  16
#define S_  16
#define HD_ 64
#define NCH 32
#define CHL 64   /* T_/NCH */

typedef short  short8  __attribute__((ext_vector_type(8)));
typedef unsigned short ushort8 __attribute__((ext_vector_type(8)));
typedef unsigned short ushort4v __attribute__((ext_vector_type(4)));
typedef float  f32x4   __attribute__((ext_vector_type(4)));

__device__ __forceinline__ float softplus_f(float v) {
    return fmaxf(v, 0.f) + log1pf(__expf(-fabsf(v)));
}

__device__ __forceinline__ unsigned short f2bf(float x) {
    unsigned u = __float_as_uint(x);
    u += 0x7fffu + ((u >> 16) & 1u);
    return (unsigned short)(u >> 16);
}

// ---------------------------------------------------------------------------
// cast fp32 -> bf16 (vectorized), n4 = n/4
// ---------------------------------------------------------------------------
__global__ __launch_bounds__(256) void cast_bf16(const float* __restrict__ in,
                                                 unsigned short* __restrict__ out,
                                                 int n4)
{
    int i = blockIdx.x * 256 + threadIdx.x;
    if (i >= n4) return;
    float4 v = ((const float4*)in)[i];
    ushort4v o = {f2bf(v.x), f2bf(v.y), f2bf(v.z), f2bf(v.w)};
    ((ushort4v*)out)[i] = o;
}

// ---------------------------------------------------------------------------
// transpose-cast: W (1024 x 1024 fp32) -> WT (1024 x 1024 bf16, transposed)
// ---------------------------------------------------------------------------
__device__ __forceinline__ void wtrans_body(const float* __restrict__ W,
                                            unsigned short* __restrict__ WT,
                                            int bx, int by, int tid)
{
    __shared__ float t[32][33];
    const int n0 = bx * 32, k0 = by * 32;
    const int tx = tid & 31, ty = tid >> 5;
#pragma unroll
    for (int p = 0; p < 4; ++p)
        t[ty + p * 8][tx] = W[(size_t)(k0 + ty + p * 8) * C_ + n0 + tx];
    __syncthreads();
#pragma unroll
    for (int p = 0; p < 4; ++p)
        WT[(size_t)(n0 + ty + p * 8) * C_ + k0 + tx] = f2bf(t[tx][ty + p * 8]);
}

__global__ __launch_bounds__(256) void wtrans(const float* __restrict__ W,
                                              unsigned short* __restrict__ WT)
{
    wtrans_body(W, WT, blockIdx.x, blockIdx.y, threadIdx.x);
}

// z: 0 Wx->Astack, 1 Wd->Astack+1024 rows, 2 Wq->Wqkv, 3 Wk->+1024, 4 Wv->+2048
__global__ __launch_bounds__(256) void wtrans_multi(
    const float* __restrict__ Wx, const float* __restrict__ Wd,
    const float* __restrict__ Wq, const float* __restrict__ Wk,
    const float* __restrict__ Wv,
    unsigned short* __restrict__ Astack, unsigned short* __restrict__ Wqkv)
{
    const float* src;
    unsigned short* dst;
    switch (blockIdx.z) {
        case 0: src = Wx; dst = Astack; break;
        case 1: src = Wd; dst = Astack + (size_t)1024 * 1024; break;
        case 2: src = Wq; dst = Wqkv; break;
        case 3: src = Wk; dst = Wqkv + (size_t)1024 * 1024; break;
        default: src = Wv; dst = Wqkv + (size_t)2048 * 1024; break;
    }
    wtrans_body(src, dst, blockIdx.x, blockIdx.y, threadIdx.x);
}

// ---------------------------------------------------------------------------
// misc prep: WB/WC transposed into Astack rows 2048..2079 + stacked biases
// ---------------------------------------------------------------------------
__global__ __launch_bounds__(256) void prep_misc(
    const float* __restrict__ WB, const float* __restrict__ WC,
    const float* __restrict__ bx, const float* __restrict__ bd,
    const float* __restrict__ bq, const float* __restrict__ bk,
    const float* __restrict__ bv,
    unsigned short* __restrict__ Astack, float* __restrict__ biasPD,
    float* __restrict__ biasQKV)
{
    int gid = blockIdx.x * 256 + threadIdx.x;
    if (gid < 32768) {
        int w = gid >> 14, rem = gid & 16383;
        int s = rem >> 10, k = rem & 1023;
        const float* src = w ? WC : WB;
        Astack[(size_t)(2048 + w * 16 + s) * 1024 + k] = f2bf(src[k * 16 + s]);
    } else {
        int id = gid - 32768;
        if (id < 2176) {
            biasPD[id] = id < 1024 ? bx[id] : (id < 2048 ? bd[id - 1024] : 0.f);
        } else {
            int id2 = id - 2176;
            if (id2 < 3072)
                biasQKV[id2] = id2 < 1024 ? bq[id2]
                             : (id2 < 2048 ? bk[id2 - 1024] : bv[id2 - 2048]);
        }
    }
}

// ---------------------------------------------------------------------------
// bf16 MFMA GEMM: acc = A(M x K) @ B(N x K)^T, both lda-strided K-major bf16.
// 128x128 tile, BK=32, 256 threads = 4 waves (2x2 of 64x64), dbuf LDS via
// global_load_lds width=16.
// mode 0: split-K partial fp32; z=0 -> outv, z=1 -> out2 (no bias)
// mode 1: fused projT. rows: [0,1024) xbaseT, [1024,2048) deltaT(softplus),
//         [2048,2064) BmT, [2064,2080) CmT; cols = b*T+t. bias = biasPD[row].
// mode 2: fused QKV. cols: [0,1024) Q heads (outv), [1024,2048) K heads (out2),
//         [2048,3072) V transposed (out3). bias = biasQKV[col].
// ---------------------------------------------------------------------------
__global__ __launch_bounds__(256) void gemm_mfma(
    const unsigned short* __restrict__ A, const unsigned short* __restrict__ Bm,
    const float* __restrict__ bias,
    void* __restrict__ outv, void* __restrict__ out2,
    void* __restrict__ out3, void* __restrict__ out4,
    int M, int N, int K, int lda, int mode)
{
    __shared__ __align__(16) unsigned short As[2][4096];
    __shared__ __align__(16) unsigned short Bs[2][4096];

    const int tid = threadIdx.x;
    const int w = tid >> 6, lane = tid & 63;
    const int lq = lane & 15, lg = lane >> 4;
    const int wm = w >> 1, wn = w & 1;
    const int mBase = blockIdx.y * 128, nBase = blockIdx.x * 128;

    A  += (size_t)blockIdx.z * K;     // split-K column offset (z=0 for others)
    Bm += (size_t)blockIdx.z * K;

    const int c0 = tid, c1 = tid + 256;
    const int rA0 = ((c0 >> 6) << 4) + (c0 & 15), kO0 = ((c0 >> 4) & 3) << 3;
    const int rA1 = ((c1 >> 6) << 4) + (c1 & 15), kO1 = ((c1 >> 4) & 3) << 3;

    f32x4 acc[4][4];
#pragma unroll
    for (int i = 0; i < 4; ++i)
#pragma unroll
        for (int j = 0; j < 4; ++j) acc[i][j] = (f32x4){0.f, 0.f, 0.f, 0.f};

    const unsigned short* ga0 = A  + (size_t)(mBase + rA0) * lda + kO0;
    const unsigned short* ga1 = A  + (size_t)(mBase + rA1) * lda + kO1;
    const unsigned short* gb0 = Bm + (size_t)(nBase + rA0) * lda + kO0;
    const unsigned short* gb1 = Bm + (size_t)(nBase + rA1) * lda + kO1;

    #define LOAD_TILES(k0v, bufv)                                              \
        do {                                                                   \
            __builtin_amdgcn_global_load_lds(                                  \
                (const __attribute__((address_space(1))) void*)(ga0 + (k0v)),  \
                (__attribute__((address_space(3))) void*)&As[bufv][(w * 64) * 8],        16, 0, 0); \
            __builtin_amdgcn_global_load_lds(                                  \
                (const __attribute__((address_space(1))) void*)(ga1 + (k0v)),  \
                (__attribute__((address_space(3))) void*)&As[bufv][(256 + w * 64) * 8],  16, 0, 0); \
            __builtin_amdgcn_global_load_lds(                                  \
                (const __attribute__((address_space(1))) void*)(gb0 + (k0v)),  \
                (__attribute__((address_space(3))) void*)&Bs[bufv][(w * 64) * 8],        16, 0, 0); \
            __builtin_amdgcn_global_load_lds(                                  \
                (const __attribute__((address_space(1))) void*)(gb1 + (k0v)),  \
                (__attribute__((address_space(3))) void*)&Bs[bufv][(256 + w * 64) * 8],  16, 0, 0); \
        } while (0)

    int buf = 0;
    LOAD_TILES(0, 0);
    for (int k0 = 0; k0 < K; k0 += 32) {
        __syncthreads();
        if (k0 + 32 < K) LOAD_TILES(k0 + 32, buf ^ 1);
        short8 a[4], b[4];
#pragma unroll
        for (int i = 0; i < 4; ++i)
            a[i] = *(const short8*)&As[buf][((wm * 4 + i) * 64 + lg * 16 + lq) * 8];
#pragma unroll
        for (int j = 0; j < 4; ++j)
            b[j] = *(const short8*)&Bs[buf][((wn * 4 + j) * 64 + lg * 16 + lq) * 8];
#pragma unroll
        for (int i = 0; i < 4; ++i)
#pragma unroll
            for (int j = 0; j < 4; ++j)
                acc[i][j] = __builtin_amdgcn_mfma_f32_16x16x32_bf16(
                    a[i], b[j], acc[i][j], 0, 0, 0);
        buf ^= 1;
    }
    #undef LOAD_TILES

    if (mode == 0) {
        float* O = blockIdx.z ? (float*)out2 : (float*)outv;
#pragma unroll
        for (int i = 0; i < 4; ++i) {
            int Rb = mBase + wm * 64 + i * 16 + lg * 4;
#pragma unroll
            for (int j = 0; j < 4; ++j) {
                int Cg = nBase + wn * 64 + j * 16 + lq;
#pragma unroll
                for (int r = 0; r < 4; ++r)
                    O[(size_t)(Rb + r) * N + Cg] = acc[i][j][r];
            }
        }
    } else if (mode == 1) {
        float* xbaseT = (float*)outv;
        float* deltaT = (float*)out2;
        float* BmT    = (float*)out3;
        float* CmT    = (float*)out4;
#pragma unroll
        for (int i = 0; i < 4; ++i) {
            int Rb = mBase + wm * 64 + i * 16 + lg * 4;
            if (Rb >= 2080) continue;
            float bb[4];
#pragma unroll
            for (int r = 0; r < 4; ++r) bb[r] = bias[Rb + r];
#pragma unroll
            for (int j = 0; j < 4; ++j) {
                int Cg = nBase + wn * 64 + j * 16 + lq;
                int b = Cg >> 11, t = Cg & (T_ - 1);
#pragma unroll
                for (int r = 0; r < 4; ++r) {
                    int R = Rb + r;
                    float v = acc[i][j][r] + bb[r];
                    if (Rb < 1024) {
                        xbaseT[((size_t)b * C_ + R) * T_ + t] = v;
                    } else if (Rb < 2048) {
                        deltaT[((size_t)b * C_ + (R - 1024)) * T_ + t] =
                            softplus_f(v);
                    } else if (Rb < 2064) {
                        BmT[((size_t)b * S_ + (R - 2048)) * T_ + t] = v;
                    } else {
                        CmT[((size_t)b * S_ + (R - 2064)) * T_ + t] = v;
                    }
                }
            }
        }
    } else { // mode 2: QKV
        unsigned short* Qb  = (unsigned short*)outv;
        unsigned short* Kb  = (unsigned short*)out2;
        unsigned short* VTb = (unsigned short*)out3;
#pragma unroll
        for (int j = 0; j < 4; ++j) {
            int Cg = nBase + wn * 64 + j * 16 + lq;
            int reg = Cg >> 10, c = Cg & 1023;
            int h = c >> 6, hd = c & 63;
            float bb = bias[Cg];
#pragma unroll
            for (int i = 0; i < 4; ++i) {
                int Rb = mBase + wm * 64 + i * 16 + lg * 4;
#pragma unroll
                for (int r = 0; r < 4; ++r) {
                    int R = Rb + r, b = R >> 11, t = R & (T_ - 1);
                    unsigned short o = f2bf(acc[i][j][r] + bb);
                    if (reg == 0)
                        Qb[(((size_t)(b * H_ + h) * T_ + t) * HD_) + hd] = o;
                    else if (reg == 1)
                        Kb[(((size_t)(b * H_ + h) * T_ + t) * HD_) + hd] = o;
                    else
                        VTb[(((size_t)(b * H_ + h) * HD_ + hd) * T_) + t] = o;
                }
            }
        }
    }
}

// ---------------------------------------------------------------------------
// combine split-K partials + bias -> d_out (fp32)
// ---------------------------------------------------------------------------
__global__ __launch_bounds__(256) void combine_out(
    const float* __restrict__ p0, const float* __restrict__ p1,
    const float* __restrict__ bo, float* __restrict__ out)
{
    int i = blockIdx.x * 256 + threadIdx.x;   // over M*N/4
    float4 a = ((const float4*)p0)[i];
    float4 b = ((const float4*)p1)[i];
    float4 bb = ((const float4*)bo)[i & 255];
    float4 o = {a.x + b.x + bb.x, a.y + b.y + bb.y,
                a.z + b.z + bb.z, a.w + b.w + bb.w};
    ((float4*)out)[i] = o;
}

// ---------------------------------------------------------------------------
// Chunked scan pass 1
// ---------------------------------------------------------------------------
__global__ __launch_bounds__(256) void scan_partial(
    const float* __restrict__ xbaseT, const float* __restrict__ deltaT,
    const float* __restrict__ BmT, const float* __restrict__ A_log,
    float* __restrict__ Pbuf, float* __restrict__ Lbuf)
{
    const int tid = threadIdx.x;
    const int s = tid & 15;
    const int cl = tid >> 4;
    const int cg = blockIdx.x & 63;
    const int k  = (blockIdx.x >> 6) & (NCH - 1);
    const int b  = blockIdx.x >> 11;
    const int c  = cg * 16 + cl;

    const float a = -__expf(A_log[c * S_ + s]);
    const int tb = k * CHL;
    const float* dp = deltaT + ((size_t)b * C_ + c) * T_ + tb;
    const float* xp = xbaseT + ((size_t)b * C_ + c) * T_ + tb;
    const float* bp = BmT + ((size_t)b * S_ + s) * T_ + tb;

    float L = 0.f, sumd = 0.f;
    for (int t0 = 0; t0 < CHL; t0 += 4) {
        float4 d4 = *(const float4*)&dp[t0];
        float4 x4 = *(const float4*)&xp[t0];
        float4 b4 = *(const float4*)&bp[t0];
        float dv[4] = {d4.x, d4.y, d4.z, d4.w};
        float xv[4] = {x4.x, x4.y, x4.z, x4.w};
        float bv[4] = {b4.x, b4.y, b4.z, b4.w};
#pragma unroll
        for (int q = 0; q < 4; ++q) {
            float bar = __expf(dv[q] * a);
            L = fmaf(bar, L, dv[q] * xv[q] * bv[q]);
            sumd += dv[q];
        }
    }
    int idx = (blockIdx.x << 8) + tid;
    Pbuf[idx] = __expf(a * sumd);
    Lbuf[idx] = L;
}

// ---------------------------------------------------------------------------
// Chunked scan pass 2
// ---------------------------------------------------------------------------
__global__ __launch_bounds__(256) void scan_final(
    const float* __restrict__ xbaseT, const float* __restrict__ deltaT,
    const float* __restrict__ BmT, const float* __restrict__ CmT,
    const float* __restrict__ A_log, const float* __restrict__ Pbuf,
    const float* __restrict__ Lbuf, float* __restrict__ hyb)
{
    const int tid = threadIdx.x;
    const int s = tid & 15;
    const int cl = tid >> 4;
    const int cg = blockIdx.x & 63;
    const int k  = (blockIdx.x >> 6) & (NCH - 1);
    const int b  = blockIdx.x >> 11;
    const int c  = cg * 16 + cl;

    float h = 0.f;
    for (int k2 = 0; k2 < k; ++k2) {
        int idx = ((((b << 5) | k2) << 6 | cg) << 8) | tid;
        h = fmaf(Pbuf[idx], h, Lbuf[idx]);
    }

    const float a = -__expf(A_log[c * S_ + s]);
    const int tb = k * CHL;
    const float* dp = deltaT + ((size_t)b * C_ + c) * T_ + tb;
    const float* xp = xbaseT + ((size_t)b * C_ + c) * T_ + tb;
    const float* bp = BmT + ((size_t)b * S_ + s) * T_ + tb;
    const float* cp = CmT + ((size_t)b * S_ + s) * T_ + tb;
    float* hp = hyb + ((size_t)b * T_ + tb) * C_ + c;

    for (int t0 = 0; t0 < CHL; t0 += 4) {
        float4 d4 = *(const float4*)&dp[t0];
        float4 x4 = *(const float4*)&xp[t0];
        float4 b4 = *(const float4*)&bp[t0];
        float4 c4 = *(const float4*)&cp[t0];
        float dv[4] = {d4.x, d4.y, d4.z, d4.w};
        float xv[4] = {x4.x, x4.y, x4.z, x4.w};
        float bv[4] = {b4.x, b4.y, b4.z, b4.w};
        float cv[4] = {c4.x, c4.y, c4.z, c4.w};
#pragma unroll
        for (int q = 0; q < 4; ++q) {
            float bar = __expf(dv[q] * a);
            h = fmaf(bar, h, dv[q] * xv[q] * bv[q]);
            float contrib = h * cv[q];
            contrib += __shfl_xor(contrib, 1, 64);
            contrib += __shfl_xor(contrib, 2, 64);
            contrib += __shfl_xor(contrib, 4, 64);
            contrib += __shfl_xor(contrib, 8, 64);
            if (s == 0) hp[(size_t)(t0 + q) * C_] = xv[q] + contrib;
        }
    }
}

// ---------------------------------------------------------------------------
// LayerNorm over C=1024, bf16 output.
// ---------------------------------------------------------------------------
__global__ __launch_bounds__(256) void layernorm_kernel(
    const float* __restrict__ in, const float* __restrict__ g,
    const float* __restrict__ beta, unsigned short* __restrict__ out)
{
    const int row = blockIdx.x;
    const float* rp = in + (size_t)row * C_;
    const int c = threadIdx.x * 4;
    float4 v = *(const float4*)&rp[c];
    float sum = v.x + v.y + v.z + v.w;
    float sq = v.x * v.x + v.y * v.y + v.z * v.z + v.w * v.w;
#pragma unroll
    for (int off = 1; off < 64; off <<= 1) {
        sum += __shfl_xor(sum, off, 64);
        sq += __shfl_xor(sq, off, 64);
    }
    __shared__ float sS[4], sQ[4];
    int wave = threadIdx.x >> 6, lane = threadIdx.x & 63;
    if (lane == 0) { sS[wave] = sum; sQ[wave] = sq; }
    __syncthreads();
    sum = sS[0] + sS[1] + sS[2] + sS[3];
    sq = sQ[0] + sQ[1] + sQ[2] + sQ[3];
    const float mu = sum * (1.f / C_);
    const float var = sq * (1.f / C_) - mu * mu;
    const float rstd = rsqrtf(var + 1e-5f);
    float4 gg = *(const float4*)&g[c];
    float4 bb = *(const float4*)&beta[c];
    ushort4v o;
    o.x = f2bf((v.x - mu) * rstd * gg.x + bb.x);
    o.y = f2bf((v.y - mu) * rstd * gg.y + bb.y);
    o.z = f2bf((v.z - mu) * rstd * gg.z + bb.z);
    o.w = f2bf((v.w - mu) * rstd * gg.w + bb.w);
    *(ushort4v*)&out[(size_t)row * C_ + c] = o;
}

// ---------------------------------------------------------------------------
// MFMA flash attention, load-balanced: each block handles the q-tile pair
// (31-p, p) -> uniform 33 K-tiles per block. 512 blocks.
// ---------------------------------------------------------------------------
#define AP 72
__global__ __launch_bounds__(256) void attn_mfma(
    const unsigned short* __restrict__ Q, const unsigned short* __restrict__ K,
    const unsigned short* __restrict__ VT, const float* __restrict__ temp,
    unsigned short* __restrict__ out)
{
    __shared__ __align__(16) unsigned short Qs[64 * AP];
    __shared__ __align__(16) unsigned short Ks[64 * AP];
    __shared__ __align__(16) unsigned short Vs[64 * AP];
    __shared__ __align__(16) unsigned short Ps[4 * 16 * AP];

    const int tid = threadIdx.x;
    const int w = tid >> 6, lane = tid & 63;
    const int lq = lane & 15, lg = lane >> 4;
    const int p  = blockIdx.x & 15;
    const int bh = blockIdx.x >> 4;
    const int b = bh >> 4, h = bh & 15;

    const float scale = softplus_f(temp[h]) * 0.125f;
    const unsigned short* Kp = K + (size_t)bh * T_ * HD_;
    const unsigned short* Vp = VT + (size_t)bh * HD_ * T_;

    for (int half = 0; half < 2; ++half) {
        const int qi = half ? p : (31 - p);
        const int qbase = qi * 64;
        const unsigned short* Qp =
            Q + (size_t)bh * T_ * HD_ + (size_t)qbase * HD_;

        {
            int c0 = tid, c1 = tid + 256;
            int r0 = c0 >> 3, o0 = (c0 & 7) << 3;
            int r1 = c1 >> 3, o1 = (c1 & 7) << 3;
            *(ushort8*)&Qs[r0 * AP + o0] =
                *(const ushort8*)&Qp[(size_t)r0 * HD_ + o0];
            *(ushort8*)&Qs[r1 * AP + o1] =
                *(const ushort8*)&Qp[(size_t)r1 * HD_ + o1];
        }

        float m_i[4], l_i[4];
        f32x4 o[4];
#pragma unroll
        for (int r = 0; r < 4; ++r) { m_i[r] = -INFINITY; l_i[r] = 0.f; }
#pragma unroll
        for (int j = 0; j < 4; ++j) o[j] = (f32x4){0.f, 0.f, 0.f, 0.f};

        const int nT = qi + 1;
        for (int jt = 0; jt < nT; ++jt) {
            const int kbase = jt * 64;
            const bool last = (jt == nT - 1);
            __syncthreads();
            {
                int c0 = tid, c1 = tid + 256;
                int r0 = c0 >> 3, o0 = (c0 & 7) << 3;
                int r1 = c1 >> 3, o1 = (c1 & 7) << 3;
                *(ushort8*)&Ks[r0 * AP + o0] =
                    *(const ushort8*)&Kp[(size_t)(kbase + r0) * HD_ + o0];
                *(ushort8*)&Ks[r1 * AP + o1] =
                    *(const ushort8*)&Kp[(size_t)(kbase + r1) * HD_ + o1];
                *(ushort8*)&Vs[r0 * AP + o0] =
                    *(const ushort8*)&Vp[(size_t)r0 * T_ + kbase + o0];
                *(ushort8*)&Vs[r1 * AP + o1] =
                    *(const ushort8*)&Vp[(size_t)r1 * T_ + kbase + o1];
            }
            __syncthreads();

            f32x4 sacc[4];
#pragma unroll
            for (int j = 0; j < 4; ++j) sacc[j] = (f32x4){0.f, 0.f, 0.f, 0.f};
#pragma unroll
            for (int s = 0; s < 2; ++s) {
                short8 qf = *(const short8*)&Qs[(w * 16 + lq) * AP + s * 32 + lg * 8];
#pragma unroll
                for (int j = 0; j < 4; ++j) {
                    short8 kf = *(const short8*)&Ks[(j * 16 + lq) * AP + s * 32 + lg * 8];
                    sacc[j] = __builtin_amdgcn_mfma_f32_16x16x32_bf16(
                        qf, kf, sacc[j], 0, 0, 0);
                }
            }

#pragma unroll
            for (int r = 0; r < 4; ++r) {
                int qrow = qbase + w * 16 + lg * 4 + r;
                float sv[4];
#pragma unroll
                for (int j = 0; j < 4; ++j) {
                    sv[j] = sacc[j][r] * scale;
                    if (last && (kbase + j * 16 + lq > qrow)) sv[j] = -INFINITY;
                }
                float mx = fmaxf(fmaxf(sv[0], sv[1]), fmaxf(sv[2], sv[3]));
                mx = fmaxf(mx, __shfl_xor(mx, 1, 64));
                mx = fmaxf(mx, __shfl_xor(mx, 2, 64));
                mx = fmaxf(mx, __shfl_xor(mx, 4, 64));
                mx = fmaxf(mx, __shfl_xor(mx, 8, 64));
                float mnew = fmaxf(m_i[r], mx);
                float alpha = __expf(m_i[r] - mnew);
                float pv[4], rs = 0.f;
#pragma unroll
                for (int j = 0; j < 4; ++j) { pv[j] = __expf(sv[j] - mnew); rs += pv[j]; }
                rs += __shfl_xor(rs, 1, 64);
                rs += __shfl_xor(rs, 2, 64);
                rs += __shfl_xor(rs, 4, 64);
                rs += __shfl_xor(rs, 8, 64);
                l_i[r] = l_i[r] * alpha + rs;
                m_i[r] = mnew;
#pragma unroll
                for (int j = 0; j < 4; ++j) o[j][r] *= alpha;
#pragma unroll
                for (int j = 0; j < 4; ++j)
                    Ps[(w * 16 + lg * 4 + r) * AP + j * 16 + lq] = f2bf(pv[j]);
            }

#pragma unroll
            for (int s = 0; s < 2; ++s) {
                short8 pf = *(const short8*)&Ps[(w * 16 + lq) * AP + s * 32 + lg * 8];
#pragma unroll
                for (int j = 0; j < 4; ++j) {
                    short8 vf = *(const short8*)&Vs[(j * 16 + lq) * AP + s * 32 + lg * 8];
                    o[j] = __builtin_amdgcn_mfma_f32_16x16x32_bf16(
                        pf, vf, o[j], 0, 0, 0);
                }
            }
        }

#pragma unroll
        for (int r = 0; r < 4; ++r) {
            float inv = 1.f / l_i[r];
            int qrow = qbase + w * 16 + lg * 4 + r;
#pragma unroll
            for (int j = 0; j < 4; ++j)
                out[((size_t)(b * T_ + qrow)) * C_ + h * 64 + j * 16 + lq] =
                    f2bf(o[j][r] * inv);
        }
        __syncthreads();
    }
}

// ---------------------------------------------------------------------------
extern "C" void kernel_launch(void* const* d_in, const int* in_sizes, int n_in,
                              void* d_out, int out_size, void* d_ws, size_t ws_size,
                              hipStream_t stream)
{
    const float* x     = (const float*)d_in[0];
    const float* A_log = (const float*)d_in[1];
    const float* Wd    = (const float*)d_in[2];
    const float* bd    = (const float*)d_in[3];
    const float* WB    = (const float*)d_in[4];
    const float* WC    = (const float*)d_in[5];
    const float* Wq    = (const float*)d_in[6];
    const float* bq    = (const float*)d_in[7];
    const float* Wk    = (const float*)d_in[8];
    const float* bk    = (const float*)d_in[9];
    const float* Wv    = (const float*)d_in[10];
    const float* bv    = (const float*)d_in[11];
    const float* Wx    = (const float*)d_in[12];
    const float* bx    = (const float*)d_in[13];
    const float* Wo    = (const float*)d_in[14];
    const float* bo    = (const float*)d_in[15];
    const float* ln_g  = (const float*)d_in[16];
    const float* ln_b  = (const float*)d_in[17];
    const float* temp  = (const float*)d_in[18];

    char* wsb = (char*)d_ws;
    const size_t MB = 1024 * 1024;
    const size_t HMB = 512 * 1024;
    // Timeline-disjoint workspace map (all offsets in MB, verified disjoint
    // per kernel launch order):
    //  [0,8):      xb (cast)          -> Pbuf/Lbuf (scan) -> hybrid (LN..QKV)
    //              -> P1 [0,16) (Wo split-K partial; hybrid/Astack/WqkvT dead)
    //  [8,12.5):   Astack + biasPD/biasQKV   (biases live through QKV)
    //  [12.5,18.5): WqkvT              (live through QKV)
    //  [18.5,20.5): deltaT head -> WoT (written post-attention)
    //  [18.5,34.5): deltaT (projT..scan_final)
    //  [20.5,28.5): Qb   (QKV..attn)  -> P0 [20.5,36.5) (Wo partial)
    //  [28.5,36.5): Kb   (QKV..attn)
    //  [34.5,50.5): xbaseT (projT..scan_final)
    //  [36.5,44.5): VTb  (QKV..attn)   over dead xbaseT
    //  [44.5,52.5): attnO (attn..Wo)   over dead xbaseT tail / dead hyb head
    //  [50.5,66.5): hyb (scan_final..layernorm)
    //  [66.5,67):  BmT/CmT
    unsigned short* xb      = (unsigned short*)(wsb);
    float* Pbuf             = (float*)(wsb);
    float* Lbuf             = (float*)(wsb + 4 * MB);
    unsigned short* hybrid  = (unsigned short*)(wsb);
    float* P1               = (float*)(wsb);
    unsigned short* Astack  = (unsigned short*)(wsb + 8 * MB);
    float* biasPD           = (float*)(wsb + 8 * MB + (size_t)2176 * 2048);
    float* biasQKV          = biasPD + 2176;
    unsigned short* WqkvT   = (unsigned short*)(wsb + 12 * MB + HMB);
    unsigned short* WoT     = (unsigned short*)(wsb + 18 * MB + HMB);
    float* deltaT           = (float*)(wsb + 18 * MB + HMB);
    float* xbaseT           = (float*)(wsb + 34 * MB + HMB);
    float* hyb              = (float*)(wsb + 50 * MB + HMB);
    float* BmT              = (float*)(wsb + 66 * MB + HMB);
    float* CmT              = BmT + (size_t)B_ * S_ * T_;
    unsigned short* Qb      = (unsigned short*)(wsb + 20 * MB + HMB);
    unsigned short* Kb      = (unsigned short*)(wsb + 28 * MB + HMB);
    unsigned short* VTb     = (unsigned short*)(wsb + 36 * MB + HMB);
    unsigned short* attnO   = (unsigned short*)(wsb + 44 * MB + HMB);
    float* P0               = (float*)(wsb + 20 * MB + HMB);

    // ---- prep ----
    cast_bf16<<<4096, 256, 0, stream>>>(x, xb, (B_ * T_ * C_) / 4);
    wtrans_multi<<<dim3(32, 32, 5), 256, 0, stream>>>(Wx, Wd, Wq, Wk, Wv,
                                                      Astack, WqkvT);
    prep_misc<<<149, 256, 0, stream>>>(WB, WC, bx, bd, bq, bk, bv,
                                       Astack, biasPD, biasQKV);

    // ---- fused projection-T GEMM ----
    gemm_mfma<<<dim3(32, 17, 1), 256, 0, stream>>>(
        Astack, xb, biasPD, xbaseT, deltaT, BmT, CmT,
        2176, 4096, 1024, 1024, 1);

    // ---- chunk-parallel scan ----
    const int scanBlocks = B_ * NCH * (C_ / 16);   // 4096
    scan_partial<<<scanBlocks, 256, 0, stream>>>(xbaseT, deltaT, BmT, A_log,
                                                 Pbuf, Lbuf);
    scan_final<<<scanBlocks, 256, 0, stream>>>(xbaseT, deltaT, BmT, CmT, A_log,
                                               Pbuf, Lbuf, hyb);

    // ---- layernorm ----
    layernorm_kernel<<<B_ * T_, 256, 0, stream>>>(hyb, ln_g, ln_b, hybrid);

    // ---- fused QKV GEMM ----
    gemm_mfma<<<dim3(24, 32, 1), 256, 0, stream>>>(
        hybrid, WqkvT, biasQKV, Qb, Kb, VTb, nullptr,
        4096, 3072, 1024, 1024, 2);

    // ---- attention ----
    attn_mfma<<<B_ * H_ * 16, 256, 0, stream>>>(Qb, Kb, VTb, temp, attnO);

    // ---- Wo transpose + split-K GEMM + combine ----
    wtrans<<<dim3(32, 32), 256, 0, stream>>>(Wo, WoT);
    gemm_mfma<<<dim3(8, 32, 2), 256, 0, stream>>>(
        attnO, WoT, nullptr, P0, P1, nullptr, nullptr,
        4096, 1024, 512, 1024, 0);
    combine_out<<<4096, 256, 0, stream>>>(P0, P1, bo, (float*)d_out);
}